// Round 3
// baseline (1508.405 us; speedup 1.0000x reference)
//
#include <hip/hip_runtime.h>

// ---------------------------------------------------------------------------
// GCN (2-branch) + GAP + MLP head, MI355X.
// R2: bf16-staged gathers. GEMM stays fp32 (inputs/accum/out) but dual-writes
// a bf16 copy of H; aggregate gathers bf16 rows (half the bytes), accumulates
// fp32. GEMM inner loop vectorized to float4 Zt reads (4 k per step).
// ---------------------------------------------------------------------------

static inline size_t align256(size_t x) { return (x + 255) & ~size_t(255); }

__device__ inline unsigned short f2bf(float f) {  // RNE fp32 -> bf16
    unsigned u = __float_as_uint(f);
    unsigned r = (u + 0x7fffu + ((u >> 16) & 1u)) >> 16;
    return (unsigned short)r;
}

// ---------------- count incoming edges (1 atomic/edge) ----------------
__global__ void count_kernel(const int* __restrict__ dst, int E, int* __restrict__ cnt) {
    int i = blockIdx.x * blockDim.x + threadIdx.x;
    int stride = gridDim.x * blockDim.x;
    for (int e = i; e < E; e += stride) atomicAdd(&cnt[dst[e]], 1);
}

// ---------------- 3-phase exclusive scan ----------------
__global__ __launch_bounds__(256) void scan_block(const int* __restrict__ cnt, int n,
                                                  int* __restrict__ rp, int* __restrict__ btot) {
    __shared__ int wsum[4];
    int b = blockIdx.x, t = threadIdx.x;
    int wave = t >> 6, lane = t & 63;
    int base = b * 1024 + t * 4;
    int v0 = (base + 0 < n) ? cnt[base + 0] : 0;
    int v1 = (base + 1 < n) ? cnt[base + 1] : 0;
    int v2 = (base + 2 < n) ? cnt[base + 2] : 0;
    int v3 = (base + 3 < n) ? cnt[base + 3] : 0;
    int tsum = v0 + v1 + v2 + v3;
    int x = tsum;
    #pragma unroll
    for (int off = 1; off < 64; off <<= 1) {
        int y = __shfl_up(x, off, 64);
        if (lane >= off) x += y;
    }
    if (lane == 63) wsum[wave] = x;
    __syncthreads();
    int woff = 0;
    #pragma unroll
    for (int i = 0; i < 3; i++) if (wave > i) woff += wsum[i];
    int texcl = woff + x - tsum;
    if (base + 0 < n) rp[base + 0] = texcl;
    if (base + 1 < n) rp[base + 1] = texcl + v0;
    if (base + 2 < n) rp[base + 2] = texcl + v0 + v1;
    if (base + 3 < n) rp[base + 3] = texcl + v0 + v1 + v2;
    if (t == 255) btot[b] = woff + x;
}

__global__ __launch_bounds__(256) void scan_tot(const int* __restrict__ btot, int nb,
                                                int* __restrict__ boff) {
    __shared__ int wsum[4];
    int t = threadIdx.x;
    int wave = t >> 6, lane = t & 63;
    int base = t * 4;
    int v0 = (base + 0 < nb) ? btot[base + 0] : 0;
    int v1 = (base + 1 < nb) ? btot[base + 1] : 0;
    int v2 = (base + 2 < nb) ? btot[base + 2] : 0;
    int v3 = (base + 3 < nb) ? btot[base + 3] : 0;
    int tsum = v0 + v1 + v2 + v3;
    int x = tsum;
    #pragma unroll
    for (int off = 1; off < 64; off <<= 1) {
        int y = __shfl_up(x, off, 64);
        if (lane >= off) x += y;
    }
    if (lane == 63) wsum[wave] = x;
    __syncthreads();
    int woff = 0;
    #pragma unroll
    for (int i = 0; i < 3; i++) if (wave > i) woff += wsum[i];
    int texcl = woff + x - tsum;
    if (base + 0 < nb) boff[base + 0] = texcl;
    if (base + 1 < nb) boff[base + 1] = texcl + v0;
    if (base + 2 < nb) boff[base + 2] = texcl + v0 + v1;
    if (base + 3 < nb) boff[base + 3] = texcl + v0 + v1 + v2;
    if (t == 255) boff[nb] = woff + x;
}

__global__ void scan_add(int* __restrict__ rp, int n, const int* __restrict__ boff, int nb) {
    int i = blockIdx.x * blockDim.x + threadIdx.x;
    if (i < n) rp[i] += boff[i >> 10];
    if (i == 0) rp[n] = boff[nb];
}

// ---------------- CSR fill: packed {src, w} records ----------------
__global__ void fill_csr(const int* __restrict__ src, const int* __restrict__ dst,
                         const float* __restrict__ w, int E,
                         const int* __restrict__ rp, int* __restrict__ cursor,
                         int2* __restrict__ csr) {
    int i = blockIdx.x * blockDim.x + threadIdx.x;
    int stride = gridDim.x * blockDim.x;
    for (int e = i; e < E; e += stride) {
        int d = dst[e];
        int pos = atomicAdd(&cursor[d], 1);
        csr[rp[d] + pos] = make_int2(src[e], __float_as_int(w[e]));
    }
}

// ---------------- per-node: degw -> dinv, dinv2 ----------------
__global__ void rowstats(const int2* __restrict__ csr, const int* __restrict__ rp, int N,
                         float* __restrict__ dinv, float* __restrict__ dinv2) {
    int n = blockIdx.x * blockDim.x + threadIdx.x;
    if (n >= N) return;
    int e = rp[n], end = rp[n + 1];
    float s = 0.f;
    for (; e < end; e++) s += __int_as_float(csr[e].y);
    float d = 1.f + s;
    float r = rsqrtf(d);
    dinv[n] = r;
    dinv2[n] = r * r;
}

// ---------------- per-edge flat: w -> w * dinv[src] ----------------
__global__ void norm_kernel(int2* __restrict__ csr, int E, const float* __restrict__ dinv) {
    int i = blockIdx.x * blockDim.x + threadIdx.x;
    int stride = gridDim.x * blockDim.x;
    for (int e = i; e < E; e += stride) {
        int2 c = csr[e];
        c.y = __float_as_int(__int_as_float(c.y) * dinv[c.x]);
        csr[e] = c;
    }
}

// ---------------- flat fp32 -> bf16 cast (8 elems/thread) ----------------
__global__ void cast_bf16(const float* __restrict__ in, size_t n8,
                          unsigned short* __restrict__ out) {
    size_t i = (size_t)blockIdx.x * blockDim.x + threadIdx.x;
    if (i >= n8) return;
    const float4* in4 = (const float4*)in;
    float4 a = in4[i * 2], b = in4[i * 2 + 1];
    ushort4 lo, hi;
    lo.x = f2bf(a.x); lo.y = f2bf(a.y); lo.z = f2bf(a.z); lo.w = f2bf(a.w);
    hi.x = f2bf(b.x); hi.y = f2bf(b.y); hi.z = f2bf(b.z); hi.w = f2bf(b.w);
    ushort4* o4 = (ushort4*)out;
    o4[i * 2] = lo;
    o4[i * 2 + 1] = hi;
}

// ---------------- aggregation (bf16 gather, fp32 accum) ----------------
// LANES = F/8; each lane handles 8 features (one 16 B uint4 of bf16).
// z[n] = dinv[n] * sum_in (w*dinv[src]) * h[src]  +  dinv2[n] * h[n]
template <int LANES>
__global__ void aggregate_bf16(const unsigned short* __restrict__ h16, int N,
                               const int* __restrict__ rp,
                               const int2* __restrict__ csr,
                               const float* __restrict__ dinv,
                               const float* __restrict__ dinv2,
                               float* __restrict__ z) {
    constexpr int GPB = 256 / LANES;
    int group = threadIdx.x / LANES;
    int lane = threadIdx.x % LANES;
    int n = blockIdx.x * GPB + group;
    if (n >= N) return;
    const uint4* h4 = (const uint4*)h16;
    float acc[8];
    #pragma unroll
    for (int i = 0; i < 8; i++) acc[i] = 0.f;

    int e = rp[n], end = rp[n + 1];
    for (; e + 3 < end; e += 4) {
        int2 c0 = csr[e], c1 = csr[e + 1], c2 = csr[e + 2], c3 = csr[e + 3];
        uint4 q0 = h4[(size_t)c0.x * LANES + lane];
        uint4 q1 = h4[(size_t)c1.x * LANES + lane];
        uint4 q2 = h4[(size_t)c2.x * LANES + lane];
        uint4 q3 = h4[(size_t)c3.x * LANES + lane];
        float n0 = __int_as_float(c0.y), n1 = __int_as_float(c1.y);
        float n2 = __int_as_float(c2.y), n3 = __int_as_float(c3.y);
        #define ACC8(q, nm)                                                   \
        {                                                                     \
            acc[0] += nm * __uint_as_float(q.x << 16);                        \
            acc[1] += nm * __uint_as_float(q.x & 0xffff0000u);                \
            acc[2] += nm * __uint_as_float(q.y << 16);                        \
            acc[3] += nm * __uint_as_float(q.y & 0xffff0000u);                \
            acc[4] += nm * __uint_as_float(q.z << 16);                        \
            acc[5] += nm * __uint_as_float(q.z & 0xffff0000u);                \
            acc[6] += nm * __uint_as_float(q.w << 16);                        \
            acc[7] += nm * __uint_as_float(q.w & 0xffff0000u);                \
        }
        ACC8(q0, n0) ACC8(q1, n1) ACC8(q2, n2) ACC8(q3, n3)
    }
    for (; e < end; e++) {
        int2 c = csr[e];
        uint4 q = h4[(size_t)c.x * LANES + lane];
        float nm = __int_as_float(c.y);
        ACC8(q, nm)
    }
    uint4 qs = h4[(size_t)n * LANES + lane];
    float di = dinv[n], d2 = dinv2[n];
    float4 o0, o1;
    o0.x = acc[0] * di + __uint_as_float(qs.x << 16) * d2;
    o0.y = acc[1] * di + __uint_as_float(qs.x & 0xffff0000u) * d2;
    o0.z = acc[2] * di + __uint_as_float(qs.y << 16) * d2;
    o0.w = acc[3] * di + __uint_as_float(qs.y & 0xffff0000u) * d2;
    o1.x = acc[4] * di + __uint_as_float(qs.z << 16) * d2;
    o1.y = acc[5] * di + __uint_as_float(qs.z & 0xffff0000u) * d2;
    o1.z = acc[6] * di + __uint_as_float(qs.w << 16) * d2;
    o1.w = acc[7] * di + __uint_as_float(qs.w & 0xffff0000u) * d2;
    float4* z4 = (float4*)z;
    size_t base = ((size_t)n * LANES + lane) * 2;
    z4[base] = o0;
    z4[base + 1] = o1;
    #undef ACC8
}

// ---------------- GEMM: H[N,128] = relu(Z[N,K] @ W[K,128] + b) ----------------
// fp32 in/accum/out; also dual-writes bf16 copy (out16) if non-null.
#define BM 64
#define BK 32
__global__ __launch_bounds__(256) void gemm_bias_relu(
    const float* __restrict__ Z, const float* __restrict__ W,
    const float* __restrict__ bias, float* __restrict__ H,
    unsigned short* __restrict__ out16, int N, int K) {
    __shared__ __attribute__((aligned(16))) float Wt[BK * 128];
    __shared__ __attribute__((aligned(16))) float Zt[BM * 36];
    int tid = threadIdx.x;
    int row0 = blockIdx.x * BM;
    int j0 = (tid & 31) * 4;
    int r0 = (tid >> 5) * 8;
    float4 acc[8];
    #pragma unroll
    for (int r = 0; r < 8; r++) acc[r] = make_float4(0.f, 0.f, 0.f, 0.f);

    for (int kt = 0; kt < K; kt += BK) {
        #pragma unroll
        for (int i = 0; i < 4; i++) {
            int fid = tid + i * 256;
            int kr = fid >> 5;
            int jc = fid & 31;
            float4 wv = *(const float4*)&W[(size_t)(kt + kr) * 128 + jc * 4];
            *(float4*)&Wt[kr * 128 + jc * 4] = wv;
        }
        #pragma unroll
        for (int i = 0; i < 2; i++) {
            int fid = tid + i * 256;
            int r = fid >> 3;
            int c = fid & 7;
            int gr = row0 + r;
            float4 zv = make_float4(0.f, 0.f, 0.f, 0.f);
            if (gr < N) zv = *(const float4*)&Z[(size_t)gr * K + kt + c * 4];
            *(float4*)&Zt[r * 36 + c * 4] = zv;
        }
        __syncthreads();
        #pragma unroll
        for (int kk = 0; kk < BK; kk += 4) {
            float4 wv0 = *(const float4*)&Wt[(kk + 0) * 128 + j0];
            float4 wv1 = *(const float4*)&Wt[(kk + 1) * 128 + j0];
            float4 wv2 = *(const float4*)&Wt[(kk + 2) * 128 + j0];
            float4 wv3 = *(const float4*)&Wt[(kk + 3) * 128 + j0];
            #pragma unroll
            for (int rr = 0; rr < 8; rr++) {
                float4 zv = *(const float4*)&Zt[(r0 + rr) * 36 + kk];
                acc[rr].x += zv.x * wv0.x + zv.y * wv1.x + zv.z * wv2.x + zv.w * wv3.x;
                acc[rr].y += zv.x * wv0.y + zv.y * wv1.y + zv.z * wv2.y + zv.w * wv3.y;
                acc[rr].z += zv.x * wv0.z + zv.y * wv1.z + zv.z * wv2.z + zv.w * wv3.z;
                acc[rr].w += zv.x * wv0.w + zv.y * wv1.w + zv.z * wv2.w + zv.w * wv3.w;
            }
        }
        __syncthreads();
    }
    float4 bv = *(const float4*)&bias[j0];
    #pragma unroll
    for (int rr = 0; rr < 8; rr++) {
        int gr = row0 + r0 + rr;
        if (gr < N) {
            float4 o;
            o.x = fmaxf(acc[rr].x + bv.x, 0.f);
            o.y = fmaxf(acc[rr].y + bv.y, 0.f);
            o.z = fmaxf(acc[rr].z + bv.z, 0.f);
            o.w = fmaxf(acc[rr].w + bv.w, 0.f);
            *(float4*)&H[(size_t)gr * 128 + j0] = o;
            if (out16) {
                ushort4 o16;
                o16.x = f2bf(o.x); o16.y = f2bf(o.y);
                o16.z = f2bf(o.z); o16.w = f2bf(o.w);
                *(ushort4*)&out16[(size_t)gr * 128 + j0] = o16;
            }
        }
    }
}

// ---------------- pooling ----------------
__device__ inline int lower_bound(const int* __restrict__ a, int n, int v) {
    int lo = 0, hi = n;
    while (lo < hi) {
        int m = (lo + hi) >> 1;
        if (a[m] < v) lo = m + 1; else hi = m;
    }
    return lo;
}

__global__ void pool_kernel(const float* __restrict__ hL, const float* __restrict__ hS,
                            const int* __restrict__ batchL, int NL,
                            const int* __restrict__ batchS, int NS,
                            float* __restrict__ pool) {
    int g = blockIdx.x;
    int f = threadIdx.x;  // 128
    int sL = lower_bound(batchL, NL, g), eL = lower_bound(batchL, NL, g + 1);
    int sS = lower_bound(batchS, NS, g), eS = lower_bound(batchS, NS, g + 1);
    float acc = 0.f;
    for (int n = sL; n < eL; n++) acc += hL[(size_t)n * 128 + f];
    for (int n = sS; n < eS; n++) acc += hS[(size_t)n * 128 + f];
    int cnt = (eL - sL) + (eS - sS);
    float c = (float)(cnt > 0 ? cnt : 1);
    pool[g * 128 + f] = acc / c;
}

// ---------------- MLP head ----------------
__global__ void mlp_kernel(const float* __restrict__ pool,
                           const float* __restrict__ W1, const float* __restrict__ b1,
                           const float* __restrict__ W2, const float* __restrict__ b2,
                           const float* __restrict__ gamma, const float* __restrict__ beta,
                           const float* __restrict__ outW, const float* __restrict__ outb,
                           float* __restrict__ d_out) {
    __shared__ float row[128];
    __shared__ float row2[128];
    int g = blockIdx.x, t = threadIdx.x;  // 128 threads
    row[t] = pool[g * 128 + t];
    __syncthreads();
    float a = b1[t];
    #pragma unroll 4
    for (int k = 0; k < 128; k++) a += row[k] * W1[k * 128 + t];
    row2[t] = a;  // no relu between lin1 and lin2 in reference
    __syncthreads();
    if (t < 64) {
        float a2 = b2[t];
        #pragma unroll 4
        for (int k = 0; k < 128; k++) a2 += row2[k] * W2[k * 64 + t];
        float rs = rsqrtf(1.0f + 1e-5f);
        float hb = a2 * rs * gamma[t] + beta[t];
        float hr = fmaxf(hb, 0.f);
        d_out[512 + g * 64 + t] = hr;
        float p = hr * outW[t];
        #pragma unroll
        for (int off = 32; off > 0; off >>= 1) p += __shfl_down(p, off, 64);
        if (t == 0) d_out[g] = p + outb[0];
    }
}

// ---------------------------------------------------------------------------
extern "C" void kernel_launch(void* const* d_in, const int* in_sizes, int n_in,
                              void* d_out, int out_size, void* d_ws, size_t ws_size,
                              hipStream_t stream) {
    const float* x_l = (const float*)d_in[0];
    const int*   ei_l = (const int*)d_in[1];
    const float* w_l = (const float*)d_in[2];
    const float* x_s = (const float*)d_in[3];
    const int*   ei_s = (const int*)d_in[4];
    const float* w_s = (const float*)d_in[5];
    const int*   batch_l = (const int*)d_in[6];
    const int*   batch_s = (const int*)d_in[7];

    const int NL = in_sizes[6];           // 100000
    const int NS = in_sizes[7];           // 50000
    const int EL = in_sizes[2];           // 1600000
    const int ES = in_sizes[5];           // 800000

    const float* Wa[4] = {(const float*)d_in[8],  (const float*)d_in[12],
                          (const float*)d_in[16], (const float*)d_in[20]};
    const float* ba[4] = {(const float*)d_in[9],  (const float*)d_in[13],
                          (const float*)d_in[17], (const float*)d_in[21]};
    const float* Wb[4] = {(const float*)d_in[10], (const float*)d_in[14],
                          (const float*)d_in[18], (const float*)d_in[22]};
    const float* bb[4] = {(const float*)d_in[11], (const float*)d_in[15],
                          (const float*)d_in[19], (const float*)d_in[23]};
    const float* lin1_W = (const float*)d_in[24];
    const float* lin1_b = (const float*)d_in[25];
    const float* lin2_W = (const float*)d_in[26];
    const float* lin2_b = (const float*)d_in[27];
    const float* bn_g = (const float*)d_in[28];
    const float* bn_b = (const float*)d_in[29];
    const float* out_W = (const float*)d_in[30];
    const float* out_b = (const float*)d_in[31];
    float* out = (float*)d_out;

    const int* src_l = ei_l;
    const int* dst_l = ei_l + EL;
    const int* src_s = ei_s;
    const int* dst_s = ei_s + ES;

    // ---- workspace carve ----
    char* p = (char*)d_ws;
    auto alloc = [&](size_t bytes) { char* r = p; p += align256(bytes); return r; };
    float* A_l = (float*)alloc((size_t)NL * 128 * 4);
    float* B_l = (float*)alloc((size_t)NL * 128 * 4);
    float* A_s = (float*)alloc((size_t)NS * 128 * 4);
    float* B_s = (float*)alloc((size_t)NS * 128 * 4);
    // bf16 stage: X16 (layer-0 input cast) aliases A16 (written by gemm0 after
    // X16 is dead — X16's only reader is the layer-0 aggregate).
    unsigned short* H16_l = (unsigned short*)alloc((size_t)NL * 128 * 2);
    unsigned short* H16_s = (unsigned short*)alloc((size_t)NS * 128 * 2);
    int2*  csr_l = (int2*)alloc((size_t)EL * 8);
    int2*  csr_s = (int2*)alloc((size_t)ES * 8);
    int*   rp_l  = (int*)alloc((size_t)(NL + 1) * 4);
    int*   rp_s  = (int*)alloc((size_t)(NS + 1) * 4);
    int*   cnt_l = (int*)alloc((size_t)NL * 4);
    int*   cnt_s = (int*)alloc((size_t)NS * 4);
    float* dinv_l  = (float*)alloc((size_t)NL * 4);
    float* dinv2_l = (float*)alloc((size_t)NL * 4);
    float* dinv_s  = (float*)alloc((size_t)NS * 4);
    float* dinv2_s = (float*)alloc((size_t)NS * 4);
    int*   btot = (int*)alloc(1032 * 4);
    int*   boff = (int*)alloc(1032 * 4);
    float* pool = (float*)alloc((size_t)512 * 128 * 4);
    (void)ws_size; (void)n_in; (void)out_size;

    const int nbL = (NL + 1023) / 1024;
    const int nbS = (NS + 1023) / 1024;

    // ---- counts ----
    hipMemsetAsync(cnt_l, 0, (size_t)NL * 4, stream);
    hipMemsetAsync(cnt_s, 0, (size_t)NS * 4, stream);
    count_kernel<<<2048, 256, 0, stream>>>(dst_l, EL, cnt_l);
    count_kernel<<<1024, 256, 0, stream>>>(dst_s, ES, cnt_s);

    // ---- scan (3-phase) ----
    scan_block<<<nbL, 256, 0, stream>>>(cnt_l, NL, rp_l, btot);
    scan_tot<<<1, 256, 0, stream>>>(btot, nbL, boff);
    scan_add<<<(NL + 255) / 256, 256, 0, stream>>>(rp_l, NL, boff, nbL);
    scan_block<<<nbS, 256, 0, stream>>>(cnt_s, NS, rp_s, btot + 516);
    scan_tot<<<1, 256, 0, stream>>>(btot + 516, nbS, boff + 516);
    scan_add<<<(NS + 255) / 256, 256, 0, stream>>>(rp_s, NS, boff + 516, nbS);

    // ---- CSR fill ----
    hipMemsetAsync(cnt_l, 0, (size_t)NL * 4, stream);  // reuse as cursor
    hipMemsetAsync(cnt_s, 0, (size_t)NS * 4, stream);
    fill_csr<<<2048, 256, 0, stream>>>(src_l, dst_l, w_l, EL, rp_l, cnt_l, csr_l);
    fill_csr<<<1024, 256, 0, stream>>>(src_s, dst_s, w_s, ES, rp_s, cnt_s, csr_s);

    // ---- degree stats + edge norm ----
    rowstats<<<(NL + 255) / 256, 256, 0, stream>>>(csr_l, rp_l, NL, dinv_l, dinv2_l);
    rowstats<<<(NS + 255) / 256, 256, 0, stream>>>(csr_s, rp_s, NS, dinv_s, dinv2_s);
    norm_kernel<<<2048, 256, 0, stream>>>(csr_l, EL, dinv_l);
    norm_kernel<<<1024, 256, 0, stream>>>(csr_s, ES, dinv_s);

    // ---- bf16 casts of layer-0 inputs ----
    {
        size_t n8l = (size_t)NL * 64 / 8;
        size_t n8s = (size_t)NS * 32 / 8;
        cast_bf16<<<(int)((n8l + 255) / 256), 256, 0, stream>>>(x_l, n8l, H16_l);
        cast_bf16<<<(int)((n8s + 255) / 256), 256, 0, stream>>>(x_s, n8s, H16_s);
    }

    // ---- large branch: layer 0 (F=64 -> 8 lanes), layers 1-3 (F=128 -> 16) ----
    aggregate_bf16<8><<<(NL + 31) / 32, 256, 0, stream>>>(
        H16_l, NL, rp_l, csr_l, dinv_l, dinv2_l, B_l);
    gemm_bias_relu<<<(NL + BM - 1) / BM, 256, 0, stream>>>(B_l, Wa[0], ba[0], A_l, H16_l,
                                                           NL, 64);
    for (int layer = 1; layer < 4; layer++) {
        aggregate_bf16<16><<<(NL + 15) / 16, 256, 0, stream>>>(
            H16_l, NL, rp_l, csr_l, dinv_l, dinv2_l, B_l);
        gemm_bias_relu<<<(NL + BM - 1) / BM, 256, 0, stream>>>(
            B_l, Wa[layer], ba[layer], A_l, (layer < 3) ? H16_l : (unsigned short*)nullptr,
            NL, 128);
    }

    // ---- small branch: layer 0 (F=32 -> 4 lanes), layers 1-3 (F=128 -> 16) ----
    aggregate_bf16<4><<<(NS + 63) / 64, 256, 0, stream>>>(
        H16_s, NS, rp_s, csr_s, dinv_s, dinv2_s, B_s);
    gemm_bias_relu<<<(NS + BM - 1) / BM, 256, 0, stream>>>(B_s, Wb[0], bb[0], A_s, H16_s,
                                                           NS, 32);
    for (int layer = 1; layer < 4; layer++) {
        aggregate_bf16<16><<<(NS + 15) / 16, 256, 0, stream>>>(
            H16_s, NS, rp_s, csr_s, dinv_s, dinv2_s, B_s);
        gemm_bias_relu<<<(NS + BM - 1) / BM, 256, 0, stream>>>(
            B_s, Wb[layer], bb[layer], A_s, (layer < 3) ? H16_s : (unsigned short*)nullptr,
            NS, 128);
    }

    // ---- pooling + head ----
    pool_kernel<<<512, 128, 0, stream>>>(A_l, A_s, batch_l, NL, batch_s, NS, pool);
    mlp_kernel<<<512, 128, 0, stream>>>(pool, lin1_W, lin1_b, lin2_W, lin2_b,
                                        bn_g, bn_b, out_W, out_b, out);
}

// Round 4
// 1350.476 us; speedup vs baseline: 1.1169x; 1.1169x over previous
//
#include <hip/hip_runtime.h>

// ---------------------------------------------------------------------------
// GCN (2-branch) + GAP + MLP head, MI355X.
// R3: GEMM restructure — W half-tile resident in LDS (one barrier), Z streamed
// from global, thread = 4 rows x 16 cols, wave-uniform (broadcast) W reads.
// Dead fp32 stores removed: intermediate layers write bf16 only; final layer
// writes fp32 only. Aggregation (bf16 gather, fp32 accum) unchanged from R2.
// ---------------------------------------------------------------------------

static inline size_t align256(size_t x) { return (x + 255) & ~size_t(255); }

__device__ inline unsigned short f2bf(float f) {  // RNE fp32 -> bf16
    unsigned u = __float_as_uint(f);
    unsigned r = (u + 0x7fffu + ((u >> 16) & 1u)) >> 16;
    return (unsigned short)r;
}
__device__ inline unsigned packbf2(float lo, float hi) {
    return (unsigned)f2bf(lo) | ((unsigned)f2bf(hi) << 16);
}

// ---------------- count incoming edges (1 atomic/edge) ----------------
__global__ void count_kernel(const int* __restrict__ dst, int E, int* __restrict__ cnt) {
    int i = blockIdx.x * blockDim.x + threadIdx.x;
    int stride = gridDim.x * blockDim.x;
    for (int e = i; e < E; e += stride) atomicAdd(&cnt[dst[e]], 1);
}

// ---------------- 3-phase exclusive scan ----------------
__global__ __launch_bounds__(256) void scan_block(const int* __restrict__ cnt, int n,
                                                  int* __restrict__ rp, int* __restrict__ btot) {
    __shared__ int wsum[4];
    int b = blockIdx.x, t = threadIdx.x;
    int wave = t >> 6, lane = t & 63;
    int base = b * 1024 + t * 4;
    int v0 = (base + 0 < n) ? cnt[base + 0] : 0;
    int v1 = (base + 1 < n) ? cnt[base + 1] : 0;
    int v2 = (base + 2 < n) ? cnt[base + 2] : 0;
    int v3 = (base + 3 < n) ? cnt[base + 3] : 0;
    int tsum = v0 + v1 + v2 + v3;
    int x = tsum;
    #pragma unroll
    for (int off = 1; off < 64; off <<= 1) {
        int y = __shfl_up(x, off, 64);
        if (lane >= off) x += y;
    }
    if (lane == 63) wsum[wave] = x;
    __syncthreads();
    int woff = 0;
    #pragma unroll
    for (int i = 0; i < 3; i++) if (wave > i) woff += wsum[i];
    int texcl = woff + x - tsum;
    if (base + 0 < n) rp[base + 0] = texcl;
    if (base + 1 < n) rp[base + 1] = texcl + v0;
    if (base + 2 < n) rp[base + 2] = texcl + v0 + v1;
    if (base + 3 < n) rp[base + 3] = texcl + v0 + v1 + v2;
    if (t == 255) btot[b] = woff + x;
}

__global__ __launch_bounds__(256) void scan_tot(const int* __restrict__ btot, int nb,
                                                int* __restrict__ boff) {
    __shared__ int wsum[4];
    int t = threadIdx.x;
    int wave = t >> 6, lane = t & 63;
    int base = t * 4;
    int v0 = (base + 0 < nb) ? btot[base + 0] : 0;
    int v1 = (base + 1 < nb) ? btot[base + 1] : 0;
    int v2 = (base + 2 < nb) ? btot[base + 2] : 0;
    int v3 = (base + 3 < nb) ? btot[base + 3] : 0;
    int tsum = v0 + v1 + v2 + v3;
    int x = tsum;
    #pragma unroll
    for (int off = 1; off < 64; off <<= 1) {
        int y = __shfl_up(x, off, 64);
        if (lane >= off) x += y;
    }
    if (lane == 63) wsum[wave] = x;
    __syncthreads();
    int woff = 0;
    #pragma unroll
    for (int i = 0; i < 3; i++) if (wave > i) woff += wsum[i];
    int texcl = woff + x - tsum;
    if (base + 0 < nb) boff[base + 0] = texcl;
    if (base + 1 < nb) boff[base + 1] = texcl + v0;
    if (base + 2 < nb) boff[base + 2] = texcl + v0 + v1;
    if (base + 3 < nb) boff[base + 3] = texcl + v0 + v1 + v2;
    if (t == 255) boff[nb] = woff + x;
}

__global__ void scan_add(int* __restrict__ rp, int n, const int* __restrict__ boff, int nb) {
    int i = blockIdx.x * blockDim.x + threadIdx.x;
    if (i < n) rp[i] += boff[i >> 10];
    if (i == 0) rp[n] = boff[nb];
}

// ---------------- CSR fill: packed {src, w} records ----------------
__global__ void fill_csr(const int* __restrict__ src, const int* __restrict__ dst,
                         const float* __restrict__ w, int E,
                         const int* __restrict__ rp, int* __restrict__ cursor,
                         int2* __restrict__ csr) {
    int i = blockIdx.x * blockDim.x + threadIdx.x;
    int stride = gridDim.x * blockDim.x;
    for (int e = i; e < E; e += stride) {
        int d = dst[e];
        int pos = atomicAdd(&cursor[d], 1);
        csr[rp[d] + pos] = make_int2(src[e], __float_as_int(w[e]));
    }
}

// ---------------- per-node: degw -> dinv, dinv2 ----------------
__global__ void rowstats(const int2* __restrict__ csr, const int* __restrict__ rp, int N,
                         float* __restrict__ dinv, float* __restrict__ dinv2) {
    int n = blockIdx.x * blockDim.x + threadIdx.x;
    if (n >= N) return;
    int e = rp[n], end = rp[n + 1];
    float s = 0.f;
    for (; e < end; e++) s += __int_as_float(csr[e].y);
    float d = 1.f + s;
    float r = rsqrtf(d);
    dinv[n] = r;
    dinv2[n] = r * r;
}

// ---------------- per-edge flat: w -> w * dinv[src] ----------------
__global__ void norm_kernel(int2* __restrict__ csr, int E, const float* __restrict__ dinv) {
    int i = blockIdx.x * blockDim.x + threadIdx.x;
    int stride = gridDim.x * blockDim.x;
    for (int e = i; e < E; e += stride) {
        int2 c = csr[e];
        c.y = __float_as_int(__int_as_float(c.y) * dinv[c.x]);
        csr[e] = c;
    }
}

// ---------------- flat fp32 -> bf16 cast (8 elems/thread) ----------------
__global__ void cast_bf16(const float* __restrict__ in, size_t n8,
                          unsigned short* __restrict__ out) {
    size_t i = (size_t)blockIdx.x * blockDim.x + threadIdx.x;
    if (i >= n8) return;
    const float4* in4 = (const float4*)in;
    float4 a = in4[i * 2], b = in4[i * 2 + 1];
    ushort4 lo, hi;
    lo.x = f2bf(a.x); lo.y = f2bf(a.y); lo.z = f2bf(a.z); lo.w = f2bf(a.w);
    hi.x = f2bf(b.x); hi.y = f2bf(b.y); hi.z = f2bf(b.z); hi.w = f2bf(b.w);
    ushort4* o4 = (ushort4*)out;
    o4[i * 2] = lo;
    o4[i * 2 + 1] = hi;
}

// ---------------- aggregation (bf16 gather, fp32 accum) ----------------
template <int LANES>
__global__ void aggregate_bf16(const unsigned short* __restrict__ h16, int N,
                               const int* __restrict__ rp,
                               const int2* __restrict__ csr,
                               const float* __restrict__ dinv,
                               const float* __restrict__ dinv2,
                               float* __restrict__ z) {
    constexpr int GPB = 256 / LANES;
    int group = threadIdx.x / LANES;
    int lane = threadIdx.x % LANES;
    int n = blockIdx.x * GPB + group;
    if (n >= N) return;
    const uint4* h4 = (const uint4*)h16;
    float acc[8];
    #pragma unroll
    for (int i = 0; i < 8; i++) acc[i] = 0.f;

    int e = rp[n], end = rp[n + 1];
    for (; e + 3 < end; e += 4) {
        int2 c0 = csr[e], c1 = csr[e + 1], c2 = csr[e + 2], c3 = csr[e + 3];
        uint4 q0 = h4[(size_t)c0.x * LANES + lane];
        uint4 q1 = h4[(size_t)c1.x * LANES + lane];
        uint4 q2 = h4[(size_t)c2.x * LANES + lane];
        uint4 q3 = h4[(size_t)c3.x * LANES + lane];
        float n0 = __int_as_float(c0.y), n1 = __int_as_float(c1.y);
        float n2 = __int_as_float(c2.y), n3 = __int_as_float(c3.y);
        #define ACC8(q, nm)                                                   \
        {                                                                     \
            acc[0] += nm * __uint_as_float(q.x << 16);                        \
            acc[1] += nm * __uint_as_float(q.x & 0xffff0000u);                \
            acc[2] += nm * __uint_as_float(q.y << 16);                        \
            acc[3] += nm * __uint_as_float(q.y & 0xffff0000u);                \
            acc[4] += nm * __uint_as_float(q.z << 16);                        \
            acc[5] += nm * __uint_as_float(q.z & 0xffff0000u);                \
            acc[6] += nm * __uint_as_float(q.w << 16);                        \
            acc[7] += nm * __uint_as_float(q.w & 0xffff0000u);                \
        }
        ACC8(q0, n0) ACC8(q1, n1) ACC8(q2, n2) ACC8(q3, n3)
    }
    for (; e < end; e++) {
        int2 c = csr[e];
        uint4 q = h4[(size_t)c.x * LANES + lane];
        float nm = __int_as_float(c.y);
        ACC8(q, nm)
    }
    uint4 qs = h4[(size_t)n * LANES + lane];
    float di = dinv[n], d2 = dinv2[n];
    float4 o0, o1;
    o0.x = acc[0] * di + __uint_as_float(qs.x << 16) * d2;
    o0.y = acc[1] * di + __uint_as_float(qs.x & 0xffff0000u) * d2;
    o0.z = acc[2] * di + __uint_as_float(qs.y << 16) * d2;
    o0.w = acc[3] * di + __uint_as_float(qs.y & 0xffff0000u) * d2;
    o1.x = acc[4] * di + __uint_as_float(qs.z << 16) * d2;
    o1.y = acc[5] * di + __uint_as_float(qs.z & 0xffff0000u) * d2;
    o1.z = acc[6] * di + __uint_as_float(qs.w << 16) * d2;
    o1.w = acc[7] * di + __uint_as_float(qs.w & 0xffff0000u) * d2;
    float4* z4 = (float4*)z;
    size_t base = ((size_t)n * LANES + lane) * 2;
    z4[base] = o0;
    z4[base + 1] = o1;
    #undef ACC8
}

// ---------------- GEMM: H[N,128] = relu(Z[N,K] @ W[K,128] + b) ----------------
// Block = 256 rows x 64 cols (blockIdx.y picks col half). W half-tile in LDS,
// loaded once, ONE barrier. Thread = 4 rows x 16 cols (64 fp32 acc). Z streamed
// from global in 8-k chunks. Wave = col-group -> W LDS reads are wave-uniform
// broadcasts (no bank conflicts). Hf / H16 outputs null-gated.
template <int K>
__global__ __launch_bounds__(256) void gemm_wlds(
    const float* __restrict__ Z, const float* __restrict__ W,
    const float* __restrict__ bias, float* __restrict__ Hf,
    unsigned short* __restrict__ H16, int N) {
    __shared__ __attribute__((aligned(16))) float Wt[K * 64];
    int tid = threadIdx.x;
    int c0 = blockIdx.y * 64;
    #pragma unroll
    for (int i = 0; i < K / 16; i++) {
        int fid = tid + i * 256;
        int k = fid >> 4, j = fid & 15;
        *(float4*)&Wt[k * 64 + j * 4] =
            *(const float4*)&W[(size_t)k * 128 + c0 + j * 4];
    }
    __syncthreads();

    int slot = tid & 63, cg = tid >> 6;
    int jc = cg * 16;  // col offset within the 64-col half
    int rbase = blockIdx.x * 256 + slot;
    int r[4];
    bool ok[4];
    #pragma unroll
    for (int i = 0; i < 4; i++) { r[i] = rbase + 64 * i; ok[i] = r[i] < N; }

    float4 acc[4][4];
    #pragma unroll
    for (int i = 0; i < 4; i++)
        #pragma unroll
        for (int j = 0; j < 4; j++) acc[i][j] = make_float4(0.f, 0.f, 0.f, 0.f);

    for (int kc = 0; kc < K; kc += 8) {
        float4 z[4][2];
        #pragma unroll
        for (int i = 0; i < 4; i++) {
            z[i][0] = make_float4(0.f, 0.f, 0.f, 0.f);
            z[i][1] = make_float4(0.f, 0.f, 0.f, 0.f);
            if (ok[i]) {
                const float* zp = &Z[(size_t)r[i] * K + kc];
                z[i][0] = *(const float4*)zp;
                z[i][1] = *(const float4*)(zp + 4);
            }
        }
        #pragma unroll
        for (int kk = 0; kk < 8; kk++) {
            const float* wr = &Wt[(kc + kk) * 64 + jc];
            float4 w0 = *(const float4*)(wr + 0);
            float4 w1 = *(const float4*)(wr + 4);
            float4 w2 = *(const float4*)(wr + 8);
            float4 w3 = *(const float4*)(wr + 12);
            #pragma unroll
            for (int i = 0; i < 4; i++) {
                float zs = ((const float*)&z[i][0])[kk];
                acc[i][0].x += zs * w0.x; acc[i][0].y += zs * w0.y;
                acc[i][0].z += zs * w0.z; acc[i][0].w += zs * w0.w;
                acc[i][1].x += zs * w1.x; acc[i][1].y += zs * w1.y;
                acc[i][1].z += zs * w1.z; acc[i][1].w += zs * w1.w;
                acc[i][2].x += zs * w2.x; acc[i][2].y += zs * w2.y;
                acc[i][2].z += zs * w2.z; acc[i][2].w += zs * w2.w;
                acc[i][3].x += zs * w3.x; acc[i][3].y += zs * w3.y;
                acc[i][3].z += zs * w3.z; acc[i][3].w += zs * w3.w;
            }
        }
    }

    float4 bv[4];
    #pragma unroll
    for (int j = 0; j < 4; j++) bv[j] = *(const float4*)&bias[c0 + jc + j * 4];

    #pragma unroll
    for (int i = 0; i < 4; i++) {
        if (!ok[i]) continue;
        float4 o[4];
        #pragma unroll
        for (int j = 0; j < 4; j++) {
            o[j].x = fmaxf(acc[i][j].x + bv[j].x, 0.f);
            o[j].y = fmaxf(acc[i][j].y + bv[j].y, 0.f);
            o[j].z = fmaxf(acc[i][j].z + bv[j].z, 0.f);
            o[j].w = fmaxf(acc[i][j].w + bv[j].w, 0.f);
        }
        size_t rowoff = (size_t)r[i] * 128 + c0 + jc;
        if (Hf) {
            #pragma unroll
            for (int j = 0; j < 4; j++) *(float4*)&Hf[rowoff + j * 4] = o[j];
        }
        if (H16) {
            uint4 q0, q1;
            q0.x = packbf2(o[0].x, o[0].y); q0.y = packbf2(o[0].z, o[0].w);
            q0.z = packbf2(o[1].x, o[1].y); q0.w = packbf2(o[1].z, o[1].w);
            q1.x = packbf2(o[2].x, o[2].y); q1.y = packbf2(o[2].z, o[2].w);
            q1.z = packbf2(o[3].x, o[3].y); q1.w = packbf2(o[3].z, o[3].w);
            *(uint4*)&H16[rowoff] = q0;
            *(uint4*)&H16[rowoff + 8] = q1;
        }
    }
}

// ---------------- pooling ----------------
__device__ inline int lower_bound(const int* __restrict__ a, int n, int v) {
    int lo = 0, hi = n;
    while (lo < hi) {
        int m = (lo + hi) >> 1;
        if (a[m] < v) lo = m + 1; else hi = m;
    }
    return lo;
}

__global__ void pool_kernel(const float* __restrict__ hL, const float* __restrict__ hS,
                            const int* __restrict__ batchL, int NL,
                            const int* __restrict__ batchS, int NS,
                            float* __restrict__ pool) {
    int g = blockIdx.x;
    int f = threadIdx.x;  // 128
    int sL = lower_bound(batchL, NL, g), eL = lower_bound(batchL, NL, g + 1);
    int sS = lower_bound(batchS, NS, g), eS = lower_bound(batchS, NS, g + 1);
    float acc = 0.f;
    for (int n = sL; n < eL; n++) acc += hL[(size_t)n * 128 + f];
    for (int n = sS; n < eS; n++) acc += hS[(size_t)n * 128 + f];
    int cnt = (eL - sL) + (eS - sS);
    float c = (float)(cnt > 0 ? cnt : 1);
    pool[g * 128 + f] = acc / c;
}

// ---------------- MLP head ----------------
__global__ void mlp_kernel(const float* __restrict__ pool,
                           const float* __restrict__ W1, const float* __restrict__ b1,
                           const float* __restrict__ W2, const float* __restrict__ b2,
                           const float* __restrict__ gamma, const float* __restrict__ beta,
                           const float* __restrict__ outW, const float* __restrict__ outb,
                           float* __restrict__ d_out) {
    __shared__ float row[128];
    __shared__ float row2[128];
    int g = blockIdx.x, t = threadIdx.x;  // 128 threads
    row[t] = pool[g * 128 + t];
    __syncthreads();
    float a = b1[t];
    #pragma unroll 4
    for (int k = 0; k < 128; k++) a += row[k] * W1[k * 128 + t];
    row2[t] = a;  // no relu between lin1 and lin2 in reference
    __syncthreads();
    if (t < 64) {
        float a2 = b2[t];
        #pragma unroll 4
        for (int k = 0; k < 128; k++) a2 += row2[k] * W2[k * 64 + t];
        float rs = rsqrtf(1.0f + 1e-5f);
        float hb = a2 * rs * gamma[t] + beta[t];
        float hr = fmaxf(hb, 0.f);
        d_out[512 + g * 64 + t] = hr;
        float p = hr * outW[t];
        #pragma unroll
        for (int off = 32; off > 0; off >>= 1) p += __shfl_down(p, off, 64);
        if (t == 0) d_out[g] = p + outb[0];
    }
}

// ---------------------------------------------------------------------------
extern "C" void kernel_launch(void* const* d_in, const int* in_sizes, int n_in,
                              void* d_out, int out_size, void* d_ws, size_t ws_size,
                              hipStream_t stream) {
    const float* x_l = (const float*)d_in[0];
    const int*   ei_l = (const int*)d_in[1];
    const float* w_l = (const float*)d_in[2];
    const float* x_s = (const float*)d_in[3];
    const int*   ei_s = (const int*)d_in[4];
    const float* w_s = (const float*)d_in[5];
    const int*   batch_l = (const int*)d_in[6];
    const int*   batch_s = (const int*)d_in[7];

    const int NL = in_sizes[6];           // 100000
    const int NS = in_sizes[7];           // 50000
    const int EL = in_sizes[2];           // 1600000
    const int ES = in_sizes[5];           // 800000

    const float* Wa[4] = {(const float*)d_in[8],  (const float*)d_in[12],
                          (const float*)d_in[16], (const float*)d_in[20]};
    const float* ba[4] = {(const float*)d_in[9],  (const float*)d_in[13],
                          (const float*)d_in[17], (const float*)d_in[21]};
    const float* Wb[4] = {(const float*)d_in[10], (const float*)d_in[14],
                          (const float*)d_in[18], (const float*)d_in[22]};
    const float* bb[4] = {(const float*)d_in[11], (const float*)d_in[15],
                          (const float*)d_in[19], (const float*)d_in[23]};
    const float* lin1_W = (const float*)d_in[24];
    const float* lin1_b = (const float*)d_in[25];
    const float* lin2_W = (const float*)d_in[26];
    const float* lin2_b = (const float*)d_in[27];
    const float* bn_g = (const float*)d_in[28];
    const float* bn_b = (const float*)d_in[29];
    const float* out_W = (const float*)d_in[30];
    const float* out_b = (const float*)d_in[31];
    float* out = (float*)d_out;

    const int* src_l = ei_l;
    const int* dst_l = ei_l + EL;
    const int* src_s = ei_s;
    const int* dst_s = ei_s + ES;

    // ---- workspace carve ----
    char* p = (char*)d_ws;
    auto alloc = [&](size_t bytes) { char* r = p; p += align256(bytes); return r; };
    float* A_l = (float*)alloc((size_t)NL * 128 * 4);   // fp32 acts (final layer only)
    float* B_l = (float*)alloc((size_t)NL * 128 * 4);   // aggregate output Z
    float* A_s = (float*)alloc((size_t)NS * 128 * 4);
    float* B_s = (float*)alloc((size_t)NS * 128 * 4);
    unsigned short* H16_l = (unsigned short*)alloc((size_t)NL * 128 * 2);
    unsigned short* H16_s = (unsigned short*)alloc((size_t)NS * 128 * 2);
    int2*  csr_l = (int2*)alloc((size_t)EL * 8);
    int2*  csr_s = (int2*)alloc((size_t)ES * 8);
    int*   rp_l  = (int*)alloc((size_t)(NL + 1) * 4);
    int*   rp_s  = (int*)alloc((size_t)(NS + 1) * 4);
    int*   cnt_l = (int*)alloc((size_t)NL * 4);
    int*   cnt_s = (int*)alloc((size_t)NS * 4);
    float* dinv_l  = (float*)alloc((size_t)NL * 4);
    float* dinv2_l = (float*)alloc((size_t)NL * 4);
    float* dinv_s  = (float*)alloc((size_t)NS * 4);
    float* dinv2_s = (float*)alloc((size_t)NS * 4);
    int*   btot = (int*)alloc(1032 * 4);
    int*   boff = (int*)alloc(1032 * 4);
    float* pool = (float*)alloc((size_t)512 * 128 * 4);
    (void)ws_size; (void)n_in; (void)out_size;

    const int nbL = (NL + 1023) / 1024;
    const int nbS = (NS + 1023) / 1024;

    // ---- counts ----
    hipMemsetAsync(cnt_l, 0, (size_t)NL * 4, stream);
    hipMemsetAsync(cnt_s, 0, (size_t)NS * 4, stream);
    count_kernel<<<2048, 256, 0, stream>>>(dst_l, EL, cnt_l);
    count_kernel<<<1024, 256, 0, stream>>>(dst_s, ES, cnt_s);

    // ---- scan (3-phase) ----
    scan_block<<<nbL, 256, 0, stream>>>(cnt_l, NL, rp_l, btot);
    scan_tot<<<1, 256, 0, stream>>>(btot, nbL, boff);
    scan_add<<<(NL + 255) / 256, 256, 0, stream>>>(rp_l, NL, boff, nbL);
    scan_block<<<nbS, 256, 0, stream>>>(cnt_s, NS, rp_s, btot + 516);
    scan_tot<<<1, 256, 0, stream>>>(btot + 516, nbS, boff + 516);
    scan_add<<<(NS + 255) / 256, 256, 0, stream>>>(rp_s, NS, boff + 516, nbS);

    // ---- CSR fill ----
    hipMemsetAsync(cnt_l, 0, (size_t)NL * 4, stream);  // reuse as cursor
    hipMemsetAsync(cnt_s, 0, (size_t)NS * 4, stream);
    fill_csr<<<2048, 256, 0, stream>>>(src_l, dst_l, w_l, EL, rp_l, cnt_l, csr_l);
    fill_csr<<<1024, 256, 0, stream>>>(src_s, dst_s, w_s, ES, rp_s, cnt_s, csr_s);

    // ---- degree stats + edge norm ----
    rowstats<<<(NL + 255) / 256, 256, 0, stream>>>(csr_l, rp_l, NL, dinv_l, dinv2_l);
    rowstats<<<(NS + 255) / 256, 256, 0, stream>>>(csr_s, rp_s, NS, dinv_s, dinv2_s);
    norm_kernel<<<2048, 256, 0, stream>>>(csr_l, EL, dinv_l);
    norm_kernel<<<1024, 256, 0, stream>>>(csr_s, ES, dinv_s);

    // ---- bf16 casts of layer-0 inputs ----
    {
        size_t n8l = (size_t)NL * 64 / 8;
        size_t n8s = (size_t)NS * 32 / 8;
        cast_bf16<<<(int)((n8l + 255) / 256), 256, 0, stream>>>(x_l, n8l, H16_l);
        cast_bf16<<<(int)((n8s + 255) / 256), 256, 0, stream>>>(x_s, n8s, H16_s);
    }

    const int gxL = (NL + 255) / 256;
    const int gxS = (NS + 255) / 256;

    // ---- large branch: layer 0 (K=64), layers 1-3 (K=128) ----
    aggregate_bf16<8><<<(NL + 31) / 32, 256, 0, stream>>>(
        H16_l, NL, rp_l, csr_l, dinv_l, dinv2_l, B_l);
    gemm_wlds<64><<<dim3(gxL, 2), 256, 0, stream>>>(B_l, Wa[0], ba[0],
                                                    (float*)nullptr, H16_l, NL);
    for (int layer = 1; layer < 4; layer++) {
        aggregate_bf16<16><<<(NL + 15) / 16, 256, 0, stream>>>(
            H16_l, NL, rp_l, csr_l, dinv_l, dinv2_l, B_l);
        if (layer < 3)
            gemm_wlds<128><<<dim3(gxL, 2), 256, 0, stream>>>(B_l, Wa[layer], ba[layer],
                                                             (float*)nullptr, H16_l, NL);
        else
            gemm_wlds<128><<<dim3(gxL, 2), 256, 0, stream>>>(B_l, Wa[layer], ba[layer],
                                                             A_l, (unsigned short*)nullptr, NL);
    }

    // ---- small branch: layer 0 (K=32), layers 1-3 (K=128) ----
    aggregate_bf16<4><<<(NS + 63) / 64, 256, 0, stream>>>(
        H16_s, NS, rp_s, csr_s, dinv_s, dinv2_s, B_s);
    gemm_wlds<32><<<dim3(gxS, 2), 256, 0, stream>>>(B_s, Wb[0], bb[0],
                                                    (float*)nullptr, H16_s, NS);
    for (int layer = 1; layer < 4; layer++) {
        aggregate_bf16<16><<<(NS + 15) / 16, 256, 0, stream>>>(
            H16_s, NS, rp_s, csr_s, dinv_s, dinv2_s, B_s);
        if (layer < 3)
            gemm_wlds<128><<<dim3(gxS, 2), 256, 0, stream>>>(B_s, Wb[layer], bb[layer],
                                                             (float*)nullptr, H16_s, NS);
        else
            gemm_wlds<128><<<dim3(gxS, 2), 256, 0, stream>>>(B_s, Wb[layer], bb[layer],
                                                             A_s, (unsigned short*)nullptr, NS);
    }

    // ---- pooling + head ----
    pool_kernel<<<512, 128, 0, stream>>>(A_l, A_s, batch_l, NL, batch_s, NS, pool);
    mlp_kernel<<<512, 128, 0, stream>>>(pool, lin1_W, lin1_b, lin2_W, lin2_b,
                                        bn_g, bn_b, out_W, out_b, out);
}

// Round 5
// 1312.052 us; speedup vs baseline: 1.1497x; 1.0293x over previous
//
#include <hip/hip_runtime.h>

// ---------------------------------------------------------------------------
// GCN (2-branch) + GAP + MLP head, MI355X.
// R4: parallel pooling — phase A: run-length segment accumulation with
// boundary atomics (batch is sorted); phase B: count-by-binary-search + divide
// folded into the MLP head. Replaces the 512-block serial pool (103 us,
// 9% occupancy, 0.9% VALUBusy).
// ---------------------------------------------------------------------------

static inline size_t align256(size_t x) { return (x + 255) & ~size_t(255); }

__device__ inline unsigned short f2bf(float f) {  // RNE fp32 -> bf16
    unsigned u = __float_as_uint(f);
    unsigned r = (u + 0x7fffu + ((u >> 16) & 1u)) >> 16;
    return (unsigned short)r;
}
__device__ inline unsigned packbf2(float lo, float hi) {
    return (unsigned)f2bf(lo) | ((unsigned)f2bf(hi) << 16);
}

// ---------------- count incoming edges (1 atomic/edge) ----------------
__global__ void count_kernel(const int* __restrict__ dst, int E, int* __restrict__ cnt) {
    int i = blockIdx.x * blockDim.x + threadIdx.x;
    int stride = gridDim.x * blockDim.x;
    for (int e = i; e < E; e += stride) atomicAdd(&cnt[dst[e]], 1);
}

// ---------------- 3-phase exclusive scan ----------------
__global__ __launch_bounds__(256) void scan_block(const int* __restrict__ cnt, int n,
                                                  int* __restrict__ rp, int* __restrict__ btot) {
    __shared__ int wsum[4];
    int b = blockIdx.x, t = threadIdx.x;
    int wave = t >> 6, lane = t & 63;
    int base = b * 1024 + t * 4;
    int v0 = (base + 0 < n) ? cnt[base + 0] : 0;
    int v1 = (base + 1 < n) ? cnt[base + 1] : 0;
    int v2 = (base + 2 < n) ? cnt[base + 2] : 0;
    int v3 = (base + 3 < n) ? cnt[base + 3] : 0;
    int tsum = v0 + v1 + v2 + v3;
    int x = tsum;
    #pragma unroll
    for (int off = 1; off < 64; off <<= 1) {
        int y = __shfl_up(x, off, 64);
        if (lane >= off) x += y;
    }
    if (lane == 63) wsum[wave] = x;
    __syncthreads();
    int woff = 0;
    #pragma unroll
    for (int i = 0; i < 3; i++) if (wave > i) woff += wsum[i];
    int texcl = woff + x - tsum;
    if (base + 0 < n) rp[base + 0] = texcl;
    if (base + 1 < n) rp[base + 1] = texcl + v0;
    if (base + 2 < n) rp[base + 2] = texcl + v0 + v1;
    if (base + 3 < n) rp[base + 3] = texcl + v0 + v1 + v2;
    if (t == 255) btot[b] = woff + x;
}

__global__ __launch_bounds__(256) void scan_tot(const int* __restrict__ btot, int nb,
                                                int* __restrict__ boff) {
    __shared__ int wsum[4];
    int t = threadIdx.x;
    int wave = t >> 6, lane = t & 63;
    int base = t * 4;
    int v0 = (base + 0 < nb) ? btot[base + 0] : 0;
    int v1 = (base + 1 < nb) ? btot[base + 1] : 0;
    int v2 = (base + 2 < nb) ? btot[base + 2] : 0;
    int v3 = (base + 3 < nb) ? btot[base + 3] : 0;
    int tsum = v0 + v1 + v2 + v3;
    int x = tsum;
    #pragma unroll
    for (int off = 1; off < 64; off <<= 1) {
        int y = __shfl_up(x, off, 64);
        if (lane >= off) x += y;
    }
    if (lane == 63) wsum[wave] = x;
    __syncthreads();
    int woff = 0;
    #pragma unroll
    for (int i = 0; i < 3; i++) if (wave > i) woff += wsum[i];
    int texcl = woff + x - tsum;
    if (base + 0 < nb) boff[base + 0] = texcl;
    if (base + 1 < nb) boff[base + 1] = texcl + v0;
    if (base + 2 < nb) boff[base + 2] = texcl + v0 + v1;
    if (base + 3 < nb) boff[base + 3] = texcl + v0 + v1 + v2;
    if (t == 255) boff[nb] = woff + x;
}

__global__ void scan_add(int* __restrict__ rp, int n, const int* __restrict__ boff, int nb) {
    int i = blockIdx.x * blockDim.x + threadIdx.x;
    if (i < n) rp[i] += boff[i >> 10];
    if (i == 0) rp[n] = boff[nb];
}

// ---------------- CSR fill: packed {src, w} records ----------------
__global__ void fill_csr(const int* __restrict__ src, const int* __restrict__ dst,
                         const float* __restrict__ w, int E,
                         const int* __restrict__ rp, int* __restrict__ cursor,
                         int2* __restrict__ csr) {
    int i = blockIdx.x * blockDim.x + threadIdx.x;
    int stride = gridDim.x * blockDim.x;
    for (int e = i; e < E; e += stride) {
        int d = dst[e];
        int pos = atomicAdd(&cursor[d], 1);
        csr[rp[d] + pos] = make_int2(src[e], __float_as_int(w[e]));
    }
}

// ---------------- per-node: degw -> dinv, dinv2 ----------------
__global__ void rowstats(const int2* __restrict__ csr, const int* __restrict__ rp, int N,
                         float* __restrict__ dinv, float* __restrict__ dinv2) {
    int n = blockIdx.x * blockDim.x + threadIdx.x;
    if (n >= N) return;
    int e = rp[n], end = rp[n + 1];
    float s = 0.f;
    for (; e < end; e++) s += __int_as_float(csr[e].y);
    float d = 1.f + s;
    float r = rsqrtf(d);
    dinv[n] = r;
    dinv2[n] = r * r;
}

// ---------------- per-edge flat: w -> w * dinv[src] ----------------
__global__ void norm_kernel(int2* __restrict__ csr, int E, const float* __restrict__ dinv) {
    int i = blockIdx.x * blockDim.x + threadIdx.x;
    int stride = gridDim.x * blockDim.x;
    for (int e = i; e < E; e += stride) {
        int2 c = csr[e];
        c.y = __float_as_int(__int_as_float(c.y) * dinv[c.x]);
        csr[e] = c;
    }
}

// ---------------- flat fp32 -> bf16 cast (8 elems/thread) ----------------
__global__ void cast_bf16(const float* __restrict__ in, size_t n8,
                          unsigned short* __restrict__ out) {
    size_t i = (size_t)blockIdx.x * blockDim.x + threadIdx.x;
    if (i >= n8) return;
    const float4* in4 = (const float4*)in;
    float4 a = in4[i * 2], b = in4[i * 2 + 1];
    ushort4 lo, hi;
    lo.x = f2bf(a.x); lo.y = f2bf(a.y); lo.z = f2bf(a.z); lo.w = f2bf(a.w);
    hi.x = f2bf(b.x); hi.y = f2bf(b.y); hi.z = f2bf(b.z); hi.w = f2bf(b.w);
    ushort4* o4 = (ushort4*)out;
    o4[i * 2] = lo;
    o4[i * 2 + 1] = hi;
}

// ---------------- aggregation (bf16 gather, fp32 accum) ----------------
template <int LANES>
__global__ void aggregate_bf16(const unsigned short* __restrict__ h16, int N,
                               const int* __restrict__ rp,
                               const int2* __restrict__ csr,
                               const float* __restrict__ dinv,
                               const float* __restrict__ dinv2,
                               float* __restrict__ z) {
    constexpr int GPB = 256 / LANES;
    int group = threadIdx.x / LANES;
    int lane = threadIdx.x % LANES;
    int n = blockIdx.x * GPB + group;
    if (n >= N) return;
    const uint4* h4 = (const uint4*)h16;
    float acc[8];
    #pragma unroll
    for (int i = 0; i < 8; i++) acc[i] = 0.f;

    int e = rp[n], end = rp[n + 1];
    for (; e + 3 < end; e += 4) {
        int2 c0 = csr[e], c1 = csr[e + 1], c2 = csr[e + 2], c3 = csr[e + 3];
        uint4 q0 = h4[(size_t)c0.x * LANES + lane];
        uint4 q1 = h4[(size_t)c1.x * LANES + lane];
        uint4 q2 = h4[(size_t)c2.x * LANES + lane];
        uint4 q3 = h4[(size_t)c3.x * LANES + lane];
        float n0 = __int_as_float(c0.y), n1 = __int_as_float(c1.y);
        float n2 = __int_as_float(c2.y), n3 = __int_as_float(c3.y);
        #define ACC8(q, nm)                                                   \
        {                                                                     \
            acc[0] += nm * __uint_as_float(q.x << 16);                        \
            acc[1] += nm * __uint_as_float(q.x & 0xffff0000u);                \
            acc[2] += nm * __uint_as_float(q.y << 16);                        \
            acc[3] += nm * __uint_as_float(q.y & 0xffff0000u);                \
            acc[4] += nm * __uint_as_float(q.z << 16);                        \
            acc[5] += nm * __uint_as_float(q.z & 0xffff0000u);                \
            acc[6] += nm * __uint_as_float(q.w << 16);                        \
            acc[7] += nm * __uint_as_float(q.w & 0xffff0000u);                \
        }
        ACC8(q0, n0) ACC8(q1, n1) ACC8(q2, n2) ACC8(q3, n3)
    }
    for (; e < end; e++) {
        int2 c = csr[e];
        uint4 q = h4[(size_t)c.x * LANES + lane];
        float nm = __int_as_float(c.y);
        ACC8(q, nm)
    }
    uint4 qs = h4[(size_t)n * LANES + lane];
    float di = dinv[n], d2 = dinv2[n];
    float4 o0, o1;
    o0.x = acc[0] * di + __uint_as_float(qs.x << 16) * d2;
    o0.y = acc[1] * di + __uint_as_float(qs.x & 0xffff0000u) * d2;
    o0.z = acc[2] * di + __uint_as_float(qs.y << 16) * d2;
    o0.w = acc[3] * di + __uint_as_float(qs.y & 0xffff0000u) * d2;
    o1.x = acc[4] * di + __uint_as_float(qs.z << 16) * d2;
    o1.y = acc[5] * di + __uint_as_float(qs.z & 0xffff0000u) * d2;
    o1.z = acc[6] * di + __uint_as_float(qs.w << 16) * d2;
    o1.w = acc[7] * di + __uint_as_float(qs.w & 0xffff0000u) * d2;
    float4* z4 = (float4*)z;
    size_t base = ((size_t)n * LANES + lane) * 2;
    z4[base] = o0;
    z4[base + 1] = o1;
    #undef ACC8
}

// ---------------- GEMM: H[N,128] = relu(Z[N,K] @ W[K,128] + b) ----------------
template <int K>
__global__ __launch_bounds__(256) void gemm_wlds(
    const float* __restrict__ Z, const float* __restrict__ W,
    const float* __restrict__ bias, float* __restrict__ Hf,
    unsigned short* __restrict__ H16, int N) {
    __shared__ __attribute__((aligned(16))) float Wt[K * 64];
    int tid = threadIdx.x;
    int c0 = blockIdx.y * 64;
    #pragma unroll
    for (int i = 0; i < K / 16; i++) {
        int fid = tid + i * 256;
        int k = fid >> 4, j = fid & 15;
        *(float4*)&Wt[k * 64 + j * 4] =
            *(const float4*)&W[(size_t)k * 128 + c0 + j * 4];
    }
    __syncthreads();

    int slot = tid & 63, cg = tid >> 6;
    int jc = cg * 16;
    int rbase = blockIdx.x * 256 + slot;
    int r[4];
    bool ok[4];
    #pragma unroll
    for (int i = 0; i < 4; i++) { r[i] = rbase + 64 * i; ok[i] = r[i] < N; }

    float4 acc[4][4];
    #pragma unroll
    for (int i = 0; i < 4; i++)
        #pragma unroll
        for (int j = 0; j < 4; j++) acc[i][j] = make_float4(0.f, 0.f, 0.f, 0.f);

    for (int kc = 0; kc < K; kc += 8) {
        float4 z[4][2];
        #pragma unroll
        for (int i = 0; i < 4; i++) {
            z[i][0] = make_float4(0.f, 0.f, 0.f, 0.f);
            z[i][1] = make_float4(0.f, 0.f, 0.f, 0.f);
            if (ok[i]) {
                const float* zp = &Z[(size_t)r[i] * K + kc];
                z[i][0] = *(const float4*)zp;
                z[i][1] = *(const float4*)(zp + 4);
            }
        }
        #pragma unroll
        for (int kk = 0; kk < 8; kk++) {
            const float* wr = &Wt[(kc + kk) * 64 + jc];
            float4 w0 = *(const float4*)(wr + 0);
            float4 w1 = *(const float4*)(wr + 4);
            float4 w2 = *(const float4*)(wr + 8);
            float4 w3 = *(const float4*)(wr + 12);
            #pragma unroll
            for (int i = 0; i < 4; i++) {
                float zs = ((const float*)&z[i][0])[kk];
                acc[i][0].x += zs * w0.x; acc[i][0].y += zs * w0.y;
                acc[i][0].z += zs * w0.z; acc[i][0].w += zs * w0.w;
                acc[i][1].x += zs * w1.x; acc[i][1].y += zs * w1.y;
                acc[i][1].z += zs * w1.z; acc[i][1].w += zs * w1.w;
                acc[i][2].x += zs * w2.x; acc[i][2].y += zs * w2.y;
                acc[i][2].z += zs * w2.z; acc[i][2].w += zs * w2.w;
                acc[i][3].x += zs * w3.x; acc[i][3].y += zs * w3.y;
                acc[i][3].z += zs * w3.z; acc[i][3].w += zs * w3.w;
            }
        }
    }

    float4 bv[4];
    #pragma unroll
    for (int j = 0; j < 4; j++) bv[j] = *(const float4*)&bias[c0 + jc + j * 4];

    #pragma unroll
    for (int i = 0; i < 4; i++) {
        if (!ok[i]) continue;
        float4 o[4];
        #pragma unroll
        for (int j = 0; j < 4; j++) {
            o[j].x = fmaxf(acc[i][j].x + bv[j].x, 0.f);
            o[j].y = fmaxf(acc[i][j].y + bv[j].y, 0.f);
            o[j].z = fmaxf(acc[i][j].z + bv[j].z, 0.f);
            o[j].w = fmaxf(acc[i][j].w + bv[j].w, 0.f);
        }
        size_t rowoff = (size_t)r[i] * 128 + c0 + jc;
        if (Hf) {
            #pragma unroll
            for (int j = 0; j < 4; j++) *(float4*)&Hf[rowoff + j * 4] = o[j];
        }
        if (H16) {
            uint4 q0, q1;
            q0.x = packbf2(o[0].x, o[0].y); q0.y = packbf2(o[0].z, o[0].w);
            q0.z = packbf2(o[1].x, o[1].y); q0.w = packbf2(o[1].z, o[1].w);
            q1.x = packbf2(o[2].x, o[2].y); q1.y = packbf2(o[2].z, o[2].w);
            q1.z = packbf2(o[3].x, o[3].y); q1.w = packbf2(o[3].z, o[3].w);
            *(uint4*)&H16[rowoff] = q0;
            *(uint4*)&H16[rowoff + 8] = q1;
        }
    }
}

// ---------------- pooling phase A: run-length segment accumulation ----------------
// 256 nodes/block; 8 node-lanes x 32 float4-lanes. batch is sorted, so each
// node-lane sees contiguous runs of equal graph id; atomicAdd only at run
// boundaries (~2 flushes/lane).
__global__ __launch_bounds__(256) void pool_accum(const float* __restrict__ h,
                                                  const int* __restrict__ batch, int N,
                                                  float* __restrict__ psum) {
    int tid = threadIdx.x;
    int f4 = tid & 31;   // float4 column
    int nl = tid >> 5;   // node lane 0..7
    int n0 = blockIdx.x * 256 + nl;
    const float4* h4 = (const float4*)h;
    float4 acc = make_float4(0.f, 0.f, 0.f, 0.f);
    int cur = -1;
    #pragma unroll 4
    for (int i = 0; i < 32; i++) {
        int n = n0 + i * 8;
        if (n >= N) break;
        int g = batch[n];
        if (g != cur) {
            if (cur >= 0) {
                float* d = &psum[(size_t)cur * 128 + f4 * 4];
                atomicAdd(d + 0, acc.x);
                atomicAdd(d + 1, acc.y);
                atomicAdd(d + 2, acc.z);
                atomicAdd(d + 3, acc.w);
            }
            cur = g;
            acc = make_float4(0.f, 0.f, 0.f, 0.f);
        }
        float4 v = h4[(size_t)n * 32 + f4];
        acc.x += v.x; acc.y += v.y; acc.z += v.z; acc.w += v.w;
    }
    if (cur >= 0) {
        float* d = &psum[(size_t)cur * 128 + f4 * 4];
        atomicAdd(d + 0, acc.x);
        atomicAdd(d + 1, acc.y);
        atomicAdd(d + 2, acc.z);
        atomicAdd(d + 3, acc.w);
    }
}

// ---------------- MLP head (divides psum by per-graph count) ----------------
__device__ inline int lower_bound(const int* __restrict__ a, int n, int v) {
    int lo = 0, hi = n;
    while (lo < hi) {
        int m = (lo + hi) >> 1;
        if (a[m] < v) lo = m + 1; else hi = m;
    }
    return lo;
}

__global__ void mlp_kernel(const float* __restrict__ psum,
                           const int* __restrict__ batchL, int NL,
                           const int* __restrict__ batchS, int NS,
                           const float* __restrict__ W1, const float* __restrict__ b1,
                           const float* __restrict__ W2, const float* __restrict__ b2,
                           const float* __restrict__ gamma, const float* __restrict__ beta,
                           const float* __restrict__ outW, const float* __restrict__ outb,
                           float* __restrict__ d_out) {
    __shared__ float row[128];
    __shared__ float row2[128];
    int g = blockIdx.x, t = threadIdx.x;  // 128 threads
    int cnt = (lower_bound(batchL, NL, g + 1) - lower_bound(batchL, NL, g)) +
              (lower_bound(batchS, NS, g + 1) - lower_bound(batchS, NS, g));
    float rcp = 1.f / (float)(cnt > 0 ? cnt : 1);
    row[t] = psum[(size_t)g * 128 + t] * rcp;
    __syncthreads();
    float a = b1[t];
    #pragma unroll 4
    for (int k = 0; k < 128; k++) a += row[k] * W1[k * 128 + t];
    row2[t] = a;  // no relu between lin1 and lin2 in reference
    __syncthreads();
    if (t < 64) {
        float a2 = b2[t];
        #pragma unroll 4
        for (int k = 0; k < 128; k++) a2 += row2[k] * W2[k * 64 + t];
        float rs = rsqrtf(1.0f + 1e-5f);
        float hb = a2 * rs * gamma[t] + beta[t];
        float hr = fmaxf(hb, 0.f);
        d_out[512 + g * 64 + t] = hr;
        float p = hr * outW[t];
        #pragma unroll
        for (int off = 32; off > 0; off >>= 1) p += __shfl_down(p, off, 64);
        if (t == 0) d_out[g] = p + outb[0];
    }
}

// ---------------------------------------------------------------------------
extern "C" void kernel_launch(void* const* d_in, const int* in_sizes, int n_in,
                              void* d_out, int out_size, void* d_ws, size_t ws_size,
                              hipStream_t stream) {
    const float* x_l = (const float*)d_in[0];
    const int*   ei_l = (const int*)d_in[1];
    const float* w_l = (const float*)d_in[2];
    const float* x_s = (const float*)d_in[3];
    const int*   ei_s = (const int*)d_in[4];
    const float* w_s = (const float*)d_in[5];
    const int*   batch_l = (const int*)d_in[6];
    const int*   batch_s = (const int*)d_in[7];

    const int NL = in_sizes[6];           // 100000
    const int NS = in_sizes[7];           // 50000
    const int EL = in_sizes[2];           // 1600000
    const int ES = in_sizes[5];           // 800000

    const float* Wa[4] = {(const float*)d_in[8],  (const float*)d_in[12],
                          (const float*)d_in[16], (const float*)d_in[20]};
    const float* ba[4] = {(const float*)d_in[9],  (const float*)d_in[13],
                          (const float*)d_in[17], (const float*)d_in[21]};
    const float* Wb[4] = {(const float*)d_in[10], (const float*)d_in[14],
                          (const float*)d_in[18], (const float*)d_in[22]};
    const float* bb[4] = {(const float*)d_in[11], (const float*)d_in[15],
                          (const float*)d_in[19], (const float*)d_in[23]};
    const float* lin1_W = (const float*)d_in[24];
    const float* lin1_b = (const float*)d_in[25];
    const float* lin2_W = (const float*)d_in[26];
    const float* lin2_b = (const float*)d_in[27];
    const float* bn_g = (const float*)d_in[28];
    const float* bn_b = (const float*)d_in[29];
    const float* out_W = (const float*)d_in[30];
    const float* out_b = (const float*)d_in[31];
    float* out = (float*)d_out;

    const int* src_l = ei_l;
    const int* dst_l = ei_l + EL;
    const int* src_s = ei_s;
    const int* dst_s = ei_s + ES;

    // ---- workspace carve ----
    char* p = (char*)d_ws;
    auto alloc = [&](size_t bytes) { char* r = p; p += align256(bytes); return r; };
    float* A_l = (float*)alloc((size_t)NL * 128 * 4);   // fp32 acts (final layer only)
    float* B_l = (float*)alloc((size_t)NL * 128 * 4);   // aggregate output Z
    float* A_s = (float*)alloc((size_t)NS * 128 * 4);
    float* B_s = (float*)alloc((size_t)NS * 128 * 4);
    unsigned short* H16_l = (unsigned short*)alloc((size_t)NL * 128 * 2);
    unsigned short* H16_s = (unsigned short*)alloc((size_t)NS * 128 * 2);
    int2*  csr_l = (int2*)alloc((size_t)EL * 8);
    int2*  csr_s = (int2*)alloc((size_t)ES * 8);
    int*   rp_l  = (int*)alloc((size_t)(NL + 1) * 4);
    int*   rp_s  = (int*)alloc((size_t)(NS + 1) * 4);
    int*   cnt_l = (int*)alloc((size_t)NL * 4);
    int*   cnt_s = (int*)alloc((size_t)NS * 4);
    float* dinv_l  = (float*)alloc((size_t)NL * 4);
    float* dinv2_l = (float*)alloc((size_t)NL * 4);
    float* dinv_s  = (float*)alloc((size_t)NS * 4);
    float* dinv2_s = (float*)alloc((size_t)NS * 4);
    int*   btot = (int*)alloc(1032 * 4);
    int*   boff = (int*)alloc(1032 * 4);
    float* psum = (float*)alloc((size_t)512 * 128 * 4);
    (void)ws_size; (void)n_in; (void)out_size;

    const int nbL = (NL + 1023) / 1024;
    const int nbS = (NS + 1023) / 1024;

    // ---- counts ----
    hipMemsetAsync(cnt_l, 0, (size_t)NL * 4, stream);
    hipMemsetAsync(cnt_s, 0, (size_t)NS * 4, stream);
    hipMemsetAsync(psum, 0, (size_t)512 * 128 * 4, stream);
    count_kernel<<<2048, 256, 0, stream>>>(dst_l, EL, cnt_l);
    count_kernel<<<1024, 256, 0, stream>>>(dst_s, ES, cnt_s);

    // ---- scan (3-phase) ----
    scan_block<<<nbL, 256, 0, stream>>>(cnt_l, NL, rp_l, btot);
    scan_tot<<<1, 256, 0, stream>>>(btot, nbL, boff);
    scan_add<<<(NL + 255) / 256, 256, 0, stream>>>(rp_l, NL, boff, nbL);
    scan_block<<<nbS, 256, 0, stream>>>(cnt_s, NS, rp_s, btot + 516);
    scan_tot<<<1, 256, 0, stream>>>(btot + 516, nbS, boff + 516);
    scan_add<<<(NS + 255) / 256, 256, 0, stream>>>(rp_s, NS, boff + 516, nbS);

    // ---- CSR fill ----
    hipMemsetAsync(cnt_l, 0, (size_t)NL * 4, stream);  // reuse as cursor
    hipMemsetAsync(cnt_s, 0, (size_t)NS * 4, stream);
    fill_csr<<<2048, 256, 0, stream>>>(src_l, dst_l, w_l, EL, rp_l, cnt_l, csr_l);
    fill_csr<<<1024, 256, 0, stream>>>(src_s, dst_s, w_s, ES, rp_s, cnt_s, csr_s);

    // ---- degree stats + edge norm ----
    rowstats<<<(NL + 255) / 256, 256, 0, stream>>>(csr_l, rp_l, NL, dinv_l, dinv2_l);
    rowstats<<<(NS + 255) / 256, 256, 0, stream>>>(csr_s, rp_s, NS, dinv_s, dinv2_s);
    norm_kernel<<<2048, 256, 0, stream>>>(csr_l, EL, dinv_l);
    norm_kernel<<<1024, 256, 0, stream>>>(csr_s, ES, dinv_s);

    // ---- bf16 casts of layer-0 inputs ----
    {
        size_t n8l = (size_t)NL * 64 / 8;
        size_t n8s = (size_t)NS * 32 / 8;
        cast_bf16<<<(int)((n8l + 255) / 256), 256, 0, stream>>>(x_l, n8l, H16_l);
        cast_bf16<<<(int)((n8s + 255) / 256), 256, 0, stream>>>(x_s, n8s, H16_s);
    }

    const int gxL = (NL + 255) / 256;
    const int gxS = (NS + 255) / 256;

    // ---- large branch: layer 0 (K=64), layers 1-3 (K=128) ----
    aggregate_bf16<8><<<(NL + 31) / 32, 256, 0, stream>>>(
        H16_l, NL, rp_l, csr_l, dinv_l, dinv2_l, B_l);
    gemm_wlds<64><<<dim3(gxL, 2), 256, 0, stream>>>(B_l, Wa[0], ba[0],
                                                    (float*)nullptr, H16_l, NL);
    for (int layer = 1; layer < 4; layer++) {
        aggregate_bf16<16><<<(NL + 15) / 16, 256, 0, stream>>>(
            H16_l, NL, rp_l, csr_l, dinv_l, dinv2_l, B_l);
        if (layer < 3)
            gemm_wlds<128><<<dim3(gxL, 2), 256, 0, stream>>>(B_l, Wa[layer], ba[layer],
                                                             (float*)nullptr, H16_l, NL);
        else
            gemm_wlds<128><<<dim3(gxL, 2), 256, 0, stream>>>(B_l, Wa[layer], ba[layer],
                                                             A_l, (unsigned short*)nullptr, NL);
    }

    // ---- small branch: layer 0 (K=32), layers 1-3 (K=128) ----
    aggregate_bf16<4><<<(NS + 63) / 64, 256, 0, stream>>>(
        H16_s, NS, rp_s, csr_s, dinv_s, dinv2_s, B_s);
    gemm_wlds<32><<<dim3(gxS, 2), 256, 0, stream>>>(B_s, Wb[0], bb[0],
                                                    (float*)nullptr, H16_s, NS);
    for (int layer = 1; layer < 4; layer++) {
        aggregate_bf16<16><<<(NS + 15) / 16, 256, 0, stream>>>(
            H16_s, NS, rp_s, csr_s, dinv_s, dinv2_s, B_s);
        if (layer < 3)
            gemm_wlds<128><<<dim3(gxS, 2), 256, 0, stream>>>(B_s, Wb[layer], bb[layer],
                                                             (float*)nullptr, H16_s, NS);
        else
            gemm_wlds<128><<<dim3(gxS, 2), 256, 0, stream>>>(B_s, Wb[layer], bb[layer],
                                                             A_s, (unsigned short*)nullptr, NS);
    }

    // ---- pooling (phase A) + head (divide folded in) ----
    pool_accum<<<(NL + 255) / 256, 256, 0, stream>>>(A_l, batch_l, NL, psum);
    pool_accum<<<(NS + 255) / 256, 256, 0, stream>>>(A_s, batch_s, NS, psum);
    mlp_kernel<<<512, 128, 0, stream>>>(psum, batch_l, NL, batch_s, NS,
                                        lin1_W, lin1_b, lin2_W, lin2_b,
                                        bn_g, bn_b, out_W, out_b, out);
}

// Round 6
// 999.042 us; speedup vs baseline: 1.5099x; 1.3133x over previous
//
#include <hip/hip_runtime.h>

// ---------------------------------------------------------------------------
// GCN (2-branch) + GAP + MLP head, MI355X.
// R5: MFMA GEMM (bf16 in, fp32 accum) replacing fp32 VALU GEMM (~600us -> ~60us
// predicted); aggregate emits bf16 Z directly; fill_csr nontemporal stores.
// ---------------------------------------------------------------------------

static inline size_t align256(size_t x) { return (x + 255) & ~size_t(255); }

__device__ inline unsigned short f2bf(float f) {  // RNE fp32 -> bf16
    unsigned u = __float_as_uint(f);
    unsigned r = (u + 0x7fffu + ((u >> 16) & 1u)) >> 16;
    return (unsigned short)r;
}
__device__ inline unsigned packbf2(float lo, float hi) {
    return (unsigned)f2bf(lo) | ((unsigned)f2bf(hi) << 16);
}

typedef __attribute__((ext_vector_type(8))) short short8;
typedef __attribute__((ext_vector_type(4))) float floatx4;

// ---------------- count incoming edges (1 atomic/edge) ----------------
__global__ void count_kernel(const int* __restrict__ dst, int E, int* __restrict__ cnt) {
    int i = blockIdx.x * blockDim.x + threadIdx.x;
    int stride = gridDim.x * blockDim.x;
    for (int e = i; e < E; e += stride) atomicAdd(&cnt[dst[e]], 1);
}

// ---------------- 3-phase exclusive scan ----------------
__global__ __launch_bounds__(256) void scan_block(const int* __restrict__ cnt, int n,
                                                  int* __restrict__ rp, int* __restrict__ btot) {
    __shared__ int wsum[4];
    int b = blockIdx.x, t = threadIdx.x;
    int wave = t >> 6, lane = t & 63;
    int base = b * 1024 + t * 4;
    int v0 = (base + 0 < n) ? cnt[base + 0] : 0;
    int v1 = (base + 1 < n) ? cnt[base + 1] : 0;
    int v2 = (base + 2 < n) ? cnt[base + 2] : 0;
    int v3 = (base + 3 < n) ? cnt[base + 3] : 0;
    int tsum = v0 + v1 + v2 + v3;
    int x = tsum;
    #pragma unroll
    for (int off = 1; off < 64; off <<= 1) {
        int y = __shfl_up(x, off, 64);
        if (lane >= off) x += y;
    }
    if (lane == 63) wsum[wave] = x;
    __syncthreads();
    int woff = 0;
    #pragma unroll
    for (int i = 0; i < 3; i++) if (wave > i) woff += wsum[i];
    int texcl = woff + x - tsum;
    if (base + 0 < n) rp[base + 0] = texcl;
    if (base + 1 < n) rp[base + 1] = texcl + v0;
    if (base + 2 < n) rp[base + 2] = texcl + v0 + v1;
    if (base + 3 < n) rp[base + 3] = texcl + v0 + v1 + v2;
    if (t == 255) btot[b] = woff + x;
}

__global__ __launch_bounds__(256) void scan_tot(const int* __restrict__ btot, int nb,
                                                int* __restrict__ boff) {
    __shared__ int wsum[4];
    int t = threadIdx.x;
    int wave = t >> 6, lane = t & 63;
    int base = t * 4;
    int v0 = (base + 0 < nb) ? btot[base + 0] : 0;
    int v1 = (base + 1 < nb) ? btot[base + 1] : 0;
    int v2 = (base + 2 < nb) ? btot[base + 2] : 0;
    int v3 = (base + 3 < nb) ? btot[base + 3] : 0;
    int tsum = v0 + v1 + v2 + v3;
    int x = tsum;
    #pragma unroll
    for (int off = 1; off < 64; off <<= 1) {
        int y = __shfl_up(x, off, 64);
        if (lane >= off) x += y;
    }
    if (lane == 63) wsum[wave] = x;
    __syncthreads();
    int woff = 0;
    #pragma unroll
    for (int i = 0; i < 3; i++) if (wave > i) woff += wsum[i];
    int texcl = woff + x - tsum;
    if (base + 0 < nb) boff[base + 0] = texcl;
    if (base + 1 < nb) boff[base + 1] = texcl + v0;
    if (base + 2 < nb) boff[base + 2] = texcl + v0 + v1;
    if (base + 3 < nb) boff[base + 3] = texcl + v0 + v1 + v2;
    if (t == 255) boff[nb] = woff + x;
}

__global__ void scan_add(int* __restrict__ rp, int n, const int* __restrict__ boff, int nb) {
    int i = blockIdx.x * blockDim.x + threadIdx.x;
    if (i < n) rp[i] += boff[i >> 10];
    if (i == 0) rp[n] = boff[nb];
}

// ---------------- CSR fill: packed {src, w}, nontemporal scatter ----------------
__global__ void fill_csr(const int* __restrict__ src, const int* __restrict__ dst,
                         const float* __restrict__ w, int E,
                         const int* __restrict__ rp, int* __restrict__ cursor,
                         int2* __restrict__ csr) {
    int i = blockIdx.x * blockDim.x + threadIdx.x;
    int stride = gridDim.x * blockDim.x;
    for (int e = i; e < E; e += stride) {
        int d = dst[e];
        int pos = atomicAdd(&cursor[d], 1);
        long long v = ((long long)(unsigned)__float_as_int(w[e]) << 32) |
                      (unsigned)src[e];
        __builtin_nontemporal_store(v, (long long*)&csr[rp[d] + pos]);
    }
}

// ---------------- per-node: degw -> dinv, dinv2 ----------------
__global__ void rowstats(const int2* __restrict__ csr, const int* __restrict__ rp, int N,
                         float* __restrict__ dinv, float* __restrict__ dinv2) {
    int n = blockIdx.x * blockDim.x + threadIdx.x;
    if (n >= N) return;
    int e = rp[n], end = rp[n + 1];
    float s = 0.f;
    for (; e < end; e++) s += __int_as_float(csr[e].y);
    float d = 1.f + s;
    float r = rsqrtf(d);
    dinv[n] = r;
    dinv2[n] = r * r;
}

// ---------------- per-edge flat: w -> w * dinv[src] ----------------
__global__ void norm_kernel(int2* __restrict__ csr, int E, const float* __restrict__ dinv) {
    int i = blockIdx.x * blockDim.x + threadIdx.x;
    int stride = gridDim.x * blockDim.x;
    for (int e = i; e < E; e += stride) {
        int2 c = csr[e];
        c.y = __float_as_int(__int_as_float(c.y) * dinv[c.x]);
        csr[e] = c;
    }
}

// ---------------- flat fp32 -> bf16 cast (8 elems/thread) ----------------
__global__ void cast_bf16(const float* __restrict__ in, size_t n8,
                          unsigned short* __restrict__ out) {
    size_t i = (size_t)blockIdx.x * blockDim.x + threadIdx.x;
    if (i >= n8) return;
    const float4* in4 = (const float4*)in;
    float4 a = in4[i * 2], b = in4[i * 2 + 1];
    ushort4 lo, hi;
    lo.x = f2bf(a.x); lo.y = f2bf(a.y); lo.z = f2bf(a.z); lo.w = f2bf(a.w);
    hi.x = f2bf(b.x); hi.y = f2bf(b.y); hi.z = f2bf(b.z); hi.w = f2bf(b.w);
    ushort4* o4 = (ushort4*)out;
    o4[i * 2] = lo;
    o4[i * 2 + 1] = hi;
}

// ---------------- weight cast + transpose: WT16[c][k] = bf16(W[k][c]) ----------
struct WCastArgs {
    const float* w[8];
    unsigned short* o[8];
    int K[8];
};
__global__ void cast_w16t(WCastArgs p) {
    int mi = blockIdx.y;
    int K = p.K[mi];
    int id = blockIdx.x * 256 + threadIdx.x;
    if (id >= K * 128) return;
    int k = id >> 7, c = id & 127;
    p.o[mi][c * K + k] = f2bf(p.w[mi][k * 128 + c]);
}

// ---------------- aggregation (bf16 gather, fp32 accum, bf16 out) ----------------
// z[n] = dinv[n] * sum_in (w*dinv[src]) * h[src]  +  dinv2[n] * h[n]
template <int LANES>
__global__ void aggregate_bf16(const unsigned short* __restrict__ h16, int N,
                               const int* __restrict__ rp,
                               const int2* __restrict__ csr,
                               const float* __restrict__ dinv,
                               const float* __restrict__ dinv2,
                               unsigned short* __restrict__ z16) {
    constexpr int GPB = 256 / LANES;
    int group = threadIdx.x / LANES;
    int lane = threadIdx.x % LANES;
    int n = blockIdx.x * GPB + group;
    if (n >= N) return;
    const uint4* h4 = (const uint4*)h16;
    float acc[8];
    #pragma unroll
    for (int i = 0; i < 8; i++) acc[i] = 0.f;

    int e = rp[n], end = rp[n + 1];
    for (; e + 3 < end; e += 4) {
        int2 c0 = csr[e], c1 = csr[e + 1], c2 = csr[e + 2], c3 = csr[e + 3];
        uint4 q0 = h4[(size_t)c0.x * LANES + lane];
        uint4 q1 = h4[(size_t)c1.x * LANES + lane];
        uint4 q2 = h4[(size_t)c2.x * LANES + lane];
        uint4 q3 = h4[(size_t)c3.x * LANES + lane];
        float n0 = __int_as_float(c0.y), n1 = __int_as_float(c1.y);
        float n2 = __int_as_float(c2.y), n3 = __int_as_float(c3.y);
        #define ACC8(q, nm)                                                   \
        {                                                                     \
            acc[0] += nm * __uint_as_float(q.x << 16);                        \
            acc[1] += nm * __uint_as_float(q.x & 0xffff0000u);                \
            acc[2] += nm * __uint_as_float(q.y << 16);                        \
            acc[3] += nm * __uint_as_float(q.y & 0xffff0000u);                \
            acc[4] += nm * __uint_as_float(q.z << 16);                        \
            acc[5] += nm * __uint_as_float(q.z & 0xffff0000u);                \
            acc[6] += nm * __uint_as_float(q.w << 16);                        \
            acc[7] += nm * __uint_as_float(q.w & 0xffff0000u);                \
        }
        ACC8(q0, n0) ACC8(q1, n1) ACC8(q2, n2) ACC8(q3, n3)
    }
    for (; e < end; e++) {
        int2 c = csr[e];
        uint4 q = h4[(size_t)c.x * LANES + lane];
        float nm = __int_as_float(c.y);
        ACC8(q, nm)
    }
    uint4 qs = h4[(size_t)n * LANES + lane];
    float di = dinv[n], d2 = dinv2[n];
    float v0 = acc[0] * di + __uint_as_float(qs.x << 16) * d2;
    float v1 = acc[1] * di + __uint_as_float(qs.x & 0xffff0000u) * d2;
    float v2 = acc[2] * di + __uint_as_float(qs.y << 16) * d2;
    float v3 = acc[3] * di + __uint_as_float(qs.y & 0xffff0000u) * d2;
    float v4 = acc[4] * di + __uint_as_float(qs.z << 16) * d2;
    float v5 = acc[5] * di + __uint_as_float(qs.z & 0xffff0000u) * d2;
    float v6 = acc[6] * di + __uint_as_float(qs.w << 16) * d2;
    float v7 = acc[7] * di + __uint_as_float(qs.w & 0xffff0000u) * d2;
    uint4 o;
    o.x = packbf2(v0, v1); o.y = packbf2(v2, v3);
    o.z = packbf2(v4, v5); o.w = packbf2(v6, v7);
    *(uint4*)&z16[(size_t)n * (LANES * 8) + lane * 8] = o;
    #undef ACC8
}

// ---------------- MFMA GEMM: H[N,128] = relu(Z16[N,K] @ W[K,128] + b) --------
// Block = 128 rows (4 waves x 32 rows), all 128 cols. WT16 (bf16, [c][k]) staged
// into LDS with +8-elem K pad (kills the 16-way bank stride; keeps 16B align).
// A-frags straight from global (line-coalesced: 16 rows x 4 k-chunks = whole
// 64B lines). mfma_f32_16x16x32_bf16, fp32 accum. C/D: col=lane&15,
// row=quad*4+reg [verified mapping]. Epilogue: bias+relu -> bf16 and/or fp32.
template <int K>
__global__ __launch_bounds__(256) void gemm_mfma(
    const unsigned short* __restrict__ Z16, const unsigned short* __restrict__ WT16,
    const float* __restrict__ bias, float* __restrict__ Hf,
    unsigned short* __restrict__ H16, int N) {
    constexpr int KP = K + 8;
    __shared__ __attribute__((aligned(16))) unsigned short WT[128 * KP];
    int tid = threadIdx.x;
    constexpr int CH = 128 * K / 8;  // 16B chunks
    for (int i = tid; i < CH; i += 256) {
        int c = i / (K / 8), kc = i % (K / 8);
        *(uint4*)&WT[c * KP + kc * 8] = *(const uint4*)&WT16[c * K + kc * 8];
    }
    __syncthreads();

    int wave = tid >> 6, lane = tid & 63;
    int m = lane & 15, quad = lane >> 4;
    int rowbase = blockIdx.x * 128 + wave * 32;

    floatx4 acc[2][8];
    #pragma unroll
    for (int t = 0; t < 2; t++)
        #pragma unroll
        for (int ct = 0; ct < 8; ct++) acc[t][ct] = (floatx4)0.f;

    for (int ks = 0; ks < K; ks += 32) {
        short8 a[2];
        #pragma unroll
        for (int t = 0; t < 2; t++) {
            int r = rowbase + t * 16 + m;
            short8 av = (short8)0;
            if (r < N) av = *(const short8*)&Z16[(size_t)r * K + ks + quad * 8];
            a[t] = av;
        }
        #pragma unroll
        for (int ct = 0; ct < 8; ct++) {
            short8 b = *(const short8*)&WT[(ct * 16 + m) * KP + ks + quad * 8];
            acc[0][ct] = __builtin_amdgcn_mfma_f32_16x16x32_bf16(a[0], b, acc[0][ct], 0, 0, 0);
            acc[1][ct] = __builtin_amdgcn_mfma_f32_16x16x32_bf16(a[1], b, acc[1][ct], 0, 0, 0);
        }
    }

    float bv[8];
    #pragma unroll
    for (int ct = 0; ct < 8; ct++) bv[ct] = bias[ct * 16 + m];

    #pragma unroll
    for (int t = 0; t < 2; t++) {
        #pragma unroll
        for (int reg = 0; reg < 4; reg++) {
            int r = rowbase + t * 16 + quad * 4 + reg;
            if (r >= N) continue;
            #pragma unroll
            for (int ct = 0; ct < 8; ct++) {
                float o = fmaxf(acc[t][ct][reg] + bv[ct], 0.f);
                size_t off = (size_t)r * 128 + ct * 16 + m;
                if (H16) H16[off] = f2bf(o);
                if (Hf) Hf[off] = o;
            }
        }
    }
}

// ---------------- pooling phase A: run-length segment accumulation ----------------
__global__ __launch_bounds__(256) void pool_accum(const float* __restrict__ h,
                                                  const int* __restrict__ batch, int N,
                                                  float* __restrict__ psum) {
    int tid = threadIdx.x;
    int f4 = tid & 31;
    int nl = tid >> 5;
    int n0 = blockIdx.x * 256 + nl;
    const float4* h4 = (const float4*)h;
    float4 acc = make_float4(0.f, 0.f, 0.f, 0.f);
    int cur = -1;
    #pragma unroll 4
    for (int i = 0; i < 32; i++) {
        int n = n0 + i * 8;
        if (n >= N) break;
        int g = batch[n];
        if (g != cur) {
            if (cur >= 0) {
                float* d = &psum[(size_t)cur * 128 + f4 * 4];
                atomicAdd(d + 0, acc.x);
                atomicAdd(d + 1, acc.y);
                atomicAdd(d + 2, acc.z);
                atomicAdd(d + 3, acc.w);
            }
            cur = g;
            acc = make_float4(0.f, 0.f, 0.f, 0.f);
        }
        float4 v = h4[(size_t)n * 32 + f4];
        acc.x += v.x; acc.y += v.y; acc.z += v.z; acc.w += v.w;
    }
    if (cur >= 0) {
        float* d = &psum[(size_t)cur * 128 + f4 * 4];
        atomicAdd(d + 0, acc.x);
        atomicAdd(d + 1, acc.y);
        atomicAdd(d + 2, acc.z);
        atomicAdd(d + 3, acc.w);
    }
}

// ---------------- MLP head (divides psum by per-graph count) ----------------
__device__ inline int lower_bound(const int* __restrict__ a, int n, int v) {
    int lo = 0, hi = n;
    while (lo < hi) {
        int m = (lo + hi) >> 1;
        if (a[m] < v) lo = m + 1; else hi = m;
    }
    return lo;
}

__global__ void mlp_kernel(const float* __restrict__ psum,
                           const int* __restrict__ batchL, int NL,
                           const int* __restrict__ batchS, int NS,
                           const float* __restrict__ W1, const float* __restrict__ b1,
                           const float* __restrict__ W2, const float* __restrict__ b2,
                           const float* __restrict__ gamma, const float* __restrict__ beta,
                           const float* __restrict__ outW, const float* __restrict__ outb,
                           float* __restrict__ d_out) {
    __shared__ float row[128];
    __shared__ float row2[128];
    int g = blockIdx.x, t = threadIdx.x;  // 128 threads
    int cnt = (lower_bound(batchL, NL, g + 1) - lower_bound(batchL, NL, g)) +
              (lower_bound(batchS, NS, g + 1) - lower_bound(batchS, NS, g));
    float rcp = 1.f / (float)(cnt > 0 ? cnt : 1);
    row[t] = psum[(size_t)g * 128 + t] * rcp;
    __syncthreads();
    float a = b1[t];
    #pragma unroll 4
    for (int k = 0; k < 128; k++) a += row[k] * W1[k * 128 + t];
    row2[t] = a;  // no relu between lin1 and lin2 in reference
    __syncthreads();
    if (t < 64) {
        float a2 = b2[t];
        #pragma unroll 4
        for (int k = 0; k < 128; k++) a2 += row2[k] * W2[k * 64 + t];
        float rs = rsqrtf(1.0f + 1e-5f);
        float hb = a2 * rs * gamma[t] + beta[t];
        float hr = fmaxf(hb, 0.f);
        d_out[512 + g * 64 + t] = hr;
        float p = hr * outW[t];
        #pragma unroll
        for (int off = 32; off > 0; off >>= 1) p += __shfl_down(p, off, 64);
        if (t == 0) d_out[g] = p + outb[0];
    }
}

// ---------------------------------------------------------------------------
extern "C" void kernel_launch(void* const* d_in, const int* in_sizes, int n_in,
                              void* d_out, int out_size, void* d_ws, size_t ws_size,
                              hipStream_t stream) {
    const float* x_l = (const float*)d_in[0];
    const int*   ei_l = (const int*)d_in[1];
    const float* w_l = (const float*)d_in[2];
    const float* x_s = (const float*)d_in[3];
    const int*   ei_s = (const int*)d_in[4];
    const float* w_s = (const float*)d_in[5];
    const int*   batch_l = (const int*)d_in[6];
    const int*   batch_s = (const int*)d_in[7];

    const int NL = in_sizes[6];           // 100000
    const int NS = in_sizes[7];           // 50000
    const int EL = in_sizes[2];           // 1600000
    const int ES = in_sizes[5];           // 800000

    const float* Wa[4] = {(const float*)d_in[8],  (const float*)d_in[12],
                          (const float*)d_in[16], (const float*)d_in[20]};
    const float* ba[4] = {(const float*)d_in[9],  (const float*)d_in[13],
                          (const float*)d_in[17], (const float*)d_in[21]};
    const float* Wb[4] = {(const float*)d_in[10], (const float*)d_in[14],
                          (const float*)d_in[18], (const float*)d_in[22]};
    const float* bb[4] = {(const float*)d_in[11], (const float*)d_in[15],
                          (const float*)d_in[19], (const float*)d_in[23]};
    const float* lin1_W = (const float*)d_in[24];
    const float* lin1_b = (const float*)d_in[25];
    const float* lin2_W = (const float*)d_in[26];
    const float* lin2_b = (const float*)d_in[27];
    const float* bn_g = (const float*)d_in[28];
    const float* bn_b = (const float*)d_in[29];
    const float* out_W = (const float*)d_in[30];
    const float* out_b = (const float*)d_in[31];
    float* out = (float*)d_out;

    const int* src_l = ei_l;
    const int* dst_l = ei_l + EL;
    const int* src_s = ei_s;
    const int* dst_s = ei_s + ES;

    // ---- workspace carve ----
    char* p = (char*)d_ws;
    auto alloc = [&](size_t bytes) { char* r = p; p += align256(bytes); return r; };
    float* A_l = (float*)alloc((size_t)NL * 128 * 4);   // final-layer fp32 acts
    float* A_s = (float*)alloc((size_t)NS * 128 * 4);
    unsigned short* Z16_l = (unsigned short*)alloc((size_t)NL * 128 * 2);
    unsigned short* Z16_s = (unsigned short*)alloc((size_t)NS * 128 * 2);
    unsigned short* H16_l = (unsigned short*)alloc((size_t)NL * 128 * 2);
    unsigned short* H16_s = (unsigned short*)alloc((size_t)NS * 128 * 2);
    int2*  csr_l = (int2*)alloc((size_t)EL * 8);
    int2*  csr_s = (int2*)alloc((size_t)ES * 8);
    int*   rp_l  = (int*)alloc((size_t)(NL + 1) * 4);
    int*   rp_s  = (int*)alloc((size_t)(NS + 1) * 4);
    int*   cnt_l = (int*)alloc((size_t)NL * 4);
    int*   cnt_s = (int*)alloc((size_t)NS * 4);
    float* dinv_l  = (float*)alloc((size_t)NL * 4);
    float* dinv2_l = (float*)alloc((size_t)NL * 4);
    float* dinv_s  = (float*)alloc((size_t)NS * 4);
    float* dinv2_s = (float*)alloc((size_t)NS * 4);
    int*   btot = (int*)alloc(1032 * 4);
    int*   boff = (int*)alloc(1032 * 4);
    float* psum = (float*)alloc((size_t)512 * 128 * 4);
    // transposed bf16 weights: [c][k] layouts
    unsigned short* WTa[4];
    unsigned short* WTb[4];
    WTa[0] = (unsigned short*)alloc((size_t)128 * 64 * 2);
    for (int i = 1; i < 4; i++) WTa[i] = (unsigned short*)alloc((size_t)128 * 128 * 2);
    WTb[0] = (unsigned short*)alloc((size_t)128 * 32 * 2);
    for (int i = 1; i < 4; i++) WTb[i] = (unsigned short*)alloc((size_t)128 * 128 * 2);
    (void)ws_size; (void)n_in; (void)out_size;

    const int nbL = (NL + 1023) / 1024;
    const int nbS = (NS + 1023) / 1024;

    // ---- counts ----
    hipMemsetAsync(cnt_l, 0, (size_t)NL * 4, stream);
    hipMemsetAsync(cnt_s, 0, (size_t)NS * 4, stream);
    hipMemsetAsync(psum, 0, (size_t)512 * 128 * 4, stream);
    count_kernel<<<2048, 256, 0, stream>>>(dst_l, EL, cnt_l);
    count_kernel<<<1024, 256, 0, stream>>>(dst_s, ES, cnt_s);

    // ---- weight cast+transpose (one launch, 8 matrices) ----
    {
        WCastArgs wa;
        for (int i = 0; i < 4; i++) {
            wa.w[i] = Wa[i]; wa.o[i] = WTa[i]; wa.K[i] = (i == 0) ? 64 : 128;
            wa.w[4 + i] = Wb[i]; wa.o[4 + i] = WTb[i]; wa.K[4 + i] = (i == 0) ? 32 : 128;
        }
        cast_w16t<<<dim3(64, 8), 256, 0, stream>>>(wa);
    }

    // ---- scan (3-phase) ----
    scan_block<<<nbL, 256, 0, stream>>>(cnt_l, NL, rp_l, btot);
    scan_tot<<<1, 256, 0, stream>>>(btot, nbL, boff);
    scan_add<<<(NL + 255) / 256, 256, 0, stream>>>(rp_l, NL, boff, nbL);
    scan_block<<<nbS, 256, 0, stream>>>(cnt_s, NS, rp_s, btot + 516);
    scan_tot<<<1, 256, 0, stream>>>(btot + 516, nbS, boff + 516);
    scan_add<<<(NS + 255) / 256, 256, 0, stream>>>(rp_s, NS, boff + 516, nbS);

    // ---- CSR fill ----
    hipMemsetAsync(cnt_l, 0, (size_t)NL * 4, stream);  // reuse as cursor
    hipMemsetAsync(cnt_s, 0, (size_t)NS * 4, stream);
    fill_csr<<<2048, 256, 0, stream>>>(src_l, dst_l, w_l, EL, rp_l, cnt_l, csr_l);
    fill_csr<<<1024, 256, 0, stream>>>(src_s, dst_s, w_s, ES, rp_s, cnt_s, csr_s);

    // ---- degree stats + edge norm ----
    rowstats<<<(NL + 255) / 256, 256, 0, stream>>>(csr_l, rp_l, NL, dinv_l, dinv2_l);
    rowstats<<<(NS + 255) / 256, 256, 0, stream>>>(csr_s, rp_s, NS, dinv_s, dinv2_s);
    norm_kernel<<<2048, 256, 0, stream>>>(csr_l, EL, dinv_l);
    norm_kernel<<<1024, 256, 0, stream>>>(csr_s, ES, dinv_s);

    // ---- bf16 casts of layer-0 inputs ----
    {
        size_t n8l = (size_t)NL * 64 / 8;
        size_t n8s = (size_t)NS * 32 / 8;
        cast_bf16<<<(int)((n8l + 255) / 256), 256, 0, stream>>>(x_l, n8l, H16_l);
        cast_bf16<<<(int)((n8s + 255) / 256), 256, 0, stream>>>(x_s, n8s, H16_s);
    }

    const int gmL = (NL + 127) / 128;
    const int gmS = (NS + 127) / 128;

    // ---- large branch: layer 0 (K=64), layers 1-3 (K=128) ----
    aggregate_bf16<8><<<(NL + 31) / 32, 256, 0, stream>>>(
        H16_l, NL, rp_l, csr_l, dinv_l, dinv2_l, Z16_l);
    gemm_mfma<64><<<gmL, 256, 0, stream>>>(Z16_l, WTa[0], ba[0],
                                           (float*)nullptr, H16_l, NL);
    for (int layer = 1; layer < 4; layer++) {
        aggregate_bf16<16><<<(NL + 15) / 16, 256, 0, stream>>>(
            H16_l, NL, rp_l, csr_l, dinv_l, dinv2_l, Z16_l);
        if (layer < 3)
            gemm_mfma<128><<<gmL, 256, 0, stream>>>(Z16_l, WTa[layer], ba[layer],
                                                    (float*)nullptr, H16_l, NL);
        else
            gemm_mfma<128><<<gmL, 256, 0, stream>>>(Z16_l, WTa[layer], ba[layer],
                                                    A_l, (unsigned short*)nullptr, NL);
    }

    // ---- small branch: layer 0 (K=32), layers 1-3 (K=128) ----
    aggregate_bf16<4><<<(NS + 63) / 64, 256, 0, stream>>>(
        H16_s, NS, rp_s, csr_s, dinv_s, dinv2_s, Z16_s);
    gemm_mfma<32><<<gmS, 256, 0, stream>>>(Z16_s, WTb[0], bb[0],
                                           (float*)nullptr, H16_s, NS);
    for (int layer = 1; layer < 4; layer++) {
        aggregate_bf16<16><<<(NS + 15) / 16, 256, 0, stream>>>(
            H16_s, NS, rp_s, csr_s, dinv_s, dinv2_s, Z16_s);
        if (layer < 3)
            gemm_mfma<128><<<gmS, 256, 0, stream>>>(Z16_s, WTb[layer], bb[layer],
                                                    (float*)nullptr, H16_s, NS);
        else
            gemm_mfma<128><<<gmS, 256, 0, stream>>>(Z16_s, WTb[layer], bb[layer],
                                                    A_s, (unsigned short*)nullptr, NS);
    }

    // ---- pooling (phase A) + head (divide folded in) ----
    pool_accum<<<(NL + 255) / 256, 256, 0, stream>>>(A_l, batch_l, NL, psum);
    pool_accum<<<(NS + 255) / 256, 256, 0, stream>>>(A_s, batch_s, NS, psum);
    mlp_kernel<<<512, 128, 0, stream>>>(psum, batch_l, NL, batch_s, NS,
                                        lin1_W, lin1_b, lin2_W, lin2_b,
                                        bn_g, bn_b, out_W, out_b, out);
}

// Round 7
// 862.161 us; speedup vs baseline: 1.7496x; 1.1588x over previous
//
#include <hip/hip_runtime.h>

// ---------------------------------------------------------------------------
// GCN (2-branch) + GAP + MLP head, MI355X.
// R6: atomic-free-ish CSR build via 256-node bucket partition (P0 hist, P1
// scan, P2 partition w/ chunk reservation, P3 per-bucket CSR+rp+dinv).
// dinv[src] folded into activations (h~ = dinv*h) -> norm/rowstats/dinv2 gone.
// MFMA GEMM (R5) unchanged except epilogue writes bf16(dinv*h).
// ---------------------------------------------------------------------------

static inline size_t align256(size_t x) { return (x + 255) & ~size_t(255); }

__device__ inline unsigned short f2bf(float f) {  // RNE fp32 -> bf16
    unsigned u = __float_as_uint(f);
    unsigned r = (u + 0x7fffu + ((u >> 16) & 1u)) >> 16;
    return (unsigned short)r;
}
__device__ inline unsigned packbf2(float lo, float hi) {
    return (unsigned)f2bf(lo) | ((unsigned)f2bf(hi) << 16);
}

typedef __attribute__((ext_vector_type(8))) short short8;
typedef __attribute__((ext_vector_type(4))) float floatx4;

#define CHUNK 4096  // edges per block in P0/P2

// ---------------- P0: bucket histogram (bucket = dst>>8) ----------------
__global__ __launch_bounds__(256) void bucket_hist(const int* __restrict__ dst, int E,
                                                   int NB, int* __restrict__ bhist) {
    __shared__ int hist[512];
    int t = threadIdx.x;
    for (int i = t; i < NB; i += 256) hist[i] = 0;
    __syncthreads();
    int base = blockIdx.x * CHUNK;
    int end = min(E, base + CHUNK);
    for (int e = base + t; e < end; e += 256) atomicAdd(&hist[dst[e] >> 8], 1);
    __syncthreads();
    for (int i = t; i < NB; i += 256) {
        int h = hist[i];
        if (h > 0) atomicAdd(&bhist[i], h);
    }
}

// ---------------- P1: scan bucket totals -> bbase, bcur; rp[N]=E ----------------
__global__ __launch_bounds__(256) void scan_buckets(const int* __restrict__ bhist, int nb,
                                                    int* __restrict__ bbase,
                                                    int* __restrict__ bcur,
                                                    int* __restrict__ rp, int N, int E) {
    __shared__ int wsum[4];
    int t = threadIdx.x;
    int wave = t >> 6, lane = t & 63;
    int i0 = 2 * t, i1 = 2 * t + 1;
    int v0 = (i0 < nb) ? bhist[i0] : 0;
    int v1 = (i1 < nb) ? bhist[i1] : 0;
    int tsum = v0 + v1;
    int x = tsum;
    #pragma unroll
    for (int off = 1; off < 64; off <<= 1) {
        int y = __shfl_up(x, off, 64);
        if (lane >= off) x += y;
    }
    if (lane == 63) wsum[wave] = x;
    __syncthreads();
    int woff = 0;
    #pragma unroll
    for (int i = 0; i < 3; i++) if (wave > i) woff += wsum[i];
    int texcl = woff + x - tsum;
    if (i0 < nb) { bbase[i0] = texcl; bcur[i0] = texcl; }
    if (i1 < nb) { bbase[i1] = texcl + v0; bcur[i1] = texcl + v0; }
    if (t == 255) { bbase[nb] = woff + x; rp[N] = E; }
}

// ---------------- P2: partition edges into bucket regions ----------------
// record: {x = src | (dst&255)<<24, y = bits(w)}
__global__ __launch_bounds__(256) void partition_edges(
    const int* __restrict__ src, const int* __restrict__ dst,
    const float* __restrict__ w, int E, int NB,
    int* __restrict__ bcur, int2* __restrict__ part) {
    __shared__ int hist[512];
    __shared__ int lcur[512];
    int t = threadIdx.x;
    for (int i = t; i < NB; i += 256) hist[i] = 0;
    __syncthreads();
    int base = blockIdx.x * CHUNK;
    int end = min(E, base + CHUNK);
    for (int e = base + t; e < end; e += 256) atomicAdd(&hist[dst[e] >> 8], 1);
    __syncthreads();
    for (int i = t; i < NB; i += 256) {
        int h = hist[i];
        if (h > 0) lcur[i] = atomicAdd(&bcur[i], h);
    }
    __syncthreads();
    for (int e = base + t; e < end; e += 256) {
        int d = dst[e];
        int b = d >> 8;
        int pos = atomicAdd(&lcur[b], 1);
        part[pos] = make_int2(src[e] | ((d & 255) << 24), __float_as_int(w[e]));
    }
}

// ---------------- P3: per-bucket CSR + rp + dinv ----------------
__global__ __launch_bounds__(256) void bucket_csr(
    const int2* __restrict__ part, const int* __restrict__ bbase, int N,
    int* __restrict__ rp, float* __restrict__ dinv, int2* __restrict__ csr) {
    __shared__ int hist[256];
    __shared__ float degw[256];
    __shared__ int wsum[4];
    int b = blockIdx.x, t = threadIdx.x;
    int node0 = b << 8;
    int nn = min(256, N - node0);
    int ebase = bbase[b], eend = bbase[b + 1];
    hist[t] = 0;
    degw[t] = 0.f;
    __syncthreads();
    for (int e = ebase + t; e < eend; e += 256) {
        int2 rec = part[e];
        int nloc = ((unsigned)rec.x) >> 24;
        atomicAdd(&hist[nloc], 1);
        atomicAdd(&degw[nloc], __int_as_float(rec.y));
    }
    __syncthreads();
    // 256-elem exclusive scan of hist
    int v = hist[t];
    int x = v;
    int wave = t >> 6, lane = t & 63;
    #pragma unroll
    for (int off = 1; off < 64; off <<= 1) {
        int y = __shfl_up(x, off, 64);
        if (lane >= off) x += y;
    }
    if (lane == 63) wsum[wave] = x;
    __syncthreads();
    int woff = 0;
    #pragma unroll
    for (int i = 0; i < 3; i++) if (wave > i) woff += wsum[i];
    int excl = woff + x - v;
    if (t < nn) {
        rp[node0 + t] = ebase + excl;
        dinv[node0 + t] = rsqrtf(1.f + degw[t]);
    }
    hist[t] = excl;  // becomes local cursor
    __syncthreads();
    for (int e = ebase + t; e < eend; e += 256) {
        int2 rec = part[e];
        int nloc = ((unsigned)rec.x) >> 24;
        int pos = ebase + atomicAdd(&hist[nloc], 1);
        csr[pos] = make_int2(rec.x & 0x00FFFFFF, rec.y);
    }
}

// ---------------- layer-0 cast: h~ = bf16(dinv[node] * x) ----------------
template <int F8>  // groups of 8 floats per row
__global__ void cast_bf16_scaled(const float* __restrict__ in, size_t n8,
                                 const float* __restrict__ dinv,
                                 unsigned short* __restrict__ out) {
    size_t i = (size_t)blockIdx.x * blockDim.x + threadIdx.x;
    if (i >= n8) return;
    float s = dinv[i / F8];
    const float4* in4 = (const float4*)in;
    float4 a = in4[i * 2], b = in4[i * 2 + 1];
    ushort4 lo, hi;
    lo.x = f2bf(a.x * s); lo.y = f2bf(a.y * s); lo.z = f2bf(a.z * s); lo.w = f2bf(a.w * s);
    hi.x = f2bf(b.x * s); hi.y = f2bf(b.y * s); hi.z = f2bf(b.z * s); hi.w = f2bf(b.w * s);
    ushort4* o4 = (ushort4*)out;
    o4[i * 2] = lo;
    o4[i * 2 + 1] = hi;
}

// ---------------- weight cast + transpose: WT16[c][k] = bf16(W[k][c]) ----------
struct WCastArgs {
    const float* w[8];
    unsigned short* o[8];
    int K[8];
};
__global__ void cast_w16t(WCastArgs p) {
    int mi = blockIdx.y;
    int K = p.K[mi];
    int id = blockIdx.x * 256 + threadIdx.x;
    if (id >= K * 128) return;
    int k = id >> 7, c = id & 127;
    p.o[mi][c * K + k] = f2bf(p.w[mi][k * 128 + c]);
}

// ---------------- aggregation: z = bf16( dinv[n] * (sum w*h~[src] + h~[n]) ) ----
template <int LANES>
__global__ void aggregate_bf16(const unsigned short* __restrict__ h16, int N,
                               const int* __restrict__ rp,
                               const int2* __restrict__ csr,
                               const float* __restrict__ dinv,
                               unsigned short* __restrict__ z16) {
    constexpr int GPB = 256 / LANES;
    int group = threadIdx.x / LANES;
    int lane = threadIdx.x % LANES;
    int n = blockIdx.x * GPB + group;
    if (n >= N) return;
    const uint4* h4 = (const uint4*)h16;
    float acc[8];
    #pragma unroll
    for (int i = 0; i < 8; i++) acc[i] = 0.f;

    int e = rp[n], end = rp[n + 1];
    for (; e + 3 < end; e += 4) {
        int2 c0 = csr[e], c1 = csr[e + 1], c2 = csr[e + 2], c3 = csr[e + 3];
        uint4 q0 = h4[(size_t)c0.x * LANES + lane];
        uint4 q1 = h4[(size_t)c1.x * LANES + lane];
        uint4 q2 = h4[(size_t)c2.x * LANES + lane];
        uint4 q3 = h4[(size_t)c3.x * LANES + lane];
        float n0 = __int_as_float(c0.y), n1 = __int_as_float(c1.y);
        float n2 = __int_as_float(c2.y), n3 = __int_as_float(c3.y);
        #define ACC8(q, nm)                                                   \
        {                                                                     \
            acc[0] += nm * __uint_as_float(q.x << 16);                        \
            acc[1] += nm * __uint_as_float(q.x & 0xffff0000u);                \
            acc[2] += nm * __uint_as_float(q.y << 16);                        \
            acc[3] += nm * __uint_as_float(q.y & 0xffff0000u);                \
            acc[4] += nm * __uint_as_float(q.z << 16);                        \
            acc[5] += nm * __uint_as_float(q.z & 0xffff0000u);                \
            acc[6] += nm * __uint_as_float(q.w << 16);                        \
            acc[7] += nm * __uint_as_float(q.w & 0xffff0000u);                \
        }
        ACC8(q0, n0) ACC8(q1, n1) ACC8(q2, n2) ACC8(q3, n3)
    }
    for (; e < end; e++) {
        int2 c = csr[e];
        uint4 q = h4[(size_t)c.x * LANES + lane];
        float nm = __int_as_float(c.y);
        ACC8(q, nm)
    }
    uint4 qs = h4[(size_t)n * LANES + lane];
    float di = dinv[n];
    float v0 = (acc[0] + __uint_as_float(qs.x << 16)) * di;
    float v1 = (acc[1] + __uint_as_float(qs.x & 0xffff0000u)) * di;
    float v2 = (acc[2] + __uint_as_float(qs.y << 16)) * di;
    float v3 = (acc[3] + __uint_as_float(qs.y & 0xffff0000u)) * di;
    float v4 = (acc[4] + __uint_as_float(qs.z << 16)) * di;
    float v5 = (acc[5] + __uint_as_float(qs.z & 0xffff0000u)) * di;
    float v6 = (acc[6] + __uint_as_float(qs.w << 16)) * di;
    float v7 = (acc[7] + __uint_as_float(qs.w & 0xffff0000u)) * di;
    uint4 o;
    o.x = packbf2(v0, v1); o.y = packbf2(v2, v3);
    o.z = packbf2(v4, v5); o.w = packbf2(v6, v7);
    *(uint4*)&z16[(size_t)n * (LANES * 8) + lane * 8] = o;
    #undef ACC8
}

// ---------------- MFMA GEMM: h = relu(Z16 @ W + b); H16 = bf16(dinv*h) --------
template <int K>
__global__ __launch_bounds__(256) void gemm_mfma(
    const unsigned short* __restrict__ Z16, const unsigned short* __restrict__ WT16,
    const float* __restrict__ bias, const float* __restrict__ dinv,
    float* __restrict__ Hf, unsigned short* __restrict__ H16, int N) {
    constexpr int KP = K + 8;
    __shared__ __attribute__((aligned(16))) unsigned short WT[128 * KP];
    int tid = threadIdx.x;
    constexpr int CH = 128 * K / 8;  // 16B chunks
    for (int i = tid; i < CH; i += 256) {
        int c = i / (K / 8), kc = i % (K / 8);
        *(uint4*)&WT[c * KP + kc * 8] = *(const uint4*)&WT16[c * K + kc * 8];
    }
    __syncthreads();

    int wave = tid >> 6, lane = tid & 63;
    int m = lane & 15, quad = lane >> 4;
    int rowbase = blockIdx.x * 128 + wave * 32;

    floatx4 acc[2][8];
    #pragma unroll
    for (int t = 0; t < 2; t++)
        #pragma unroll
        for (int ct = 0; ct < 8; ct++) acc[t][ct] = (floatx4)0.f;

    for (int ks = 0; ks < K; ks += 32) {
        short8 a[2];
        #pragma unroll
        for (int t = 0; t < 2; t++) {
            int r = rowbase + t * 16 + m;
            short8 av = (short8)0;
            if (r < N) av = *(const short8*)&Z16[(size_t)r * K + ks + quad * 8];
            a[t] = av;
        }
        #pragma unroll
        for (int ct = 0; ct < 8; ct++) {
            short8 b = *(const short8*)&WT[(ct * 16 + m) * KP + ks + quad * 8];
            acc[0][ct] = __builtin_amdgcn_mfma_f32_16x16x32_bf16(a[0], b, acc[0][ct], 0, 0, 0);
            acc[1][ct] = __builtin_amdgcn_mfma_f32_16x16x32_bf16(a[1], b, acc[1][ct], 0, 0, 0);
        }
    }

    float bv[8];
    #pragma unroll
    for (int ct = 0; ct < 8; ct++) bv[ct] = bias[ct * 16 + m];

    #pragma unroll
    for (int t = 0; t < 2; t++) {
        #pragma unroll
        for (int reg = 0; reg < 4; reg++) {
            int r = rowbase + t * 16 + quad * 4 + reg;
            if (r >= N) continue;
            float di = H16 ? dinv[r] : 1.f;
            #pragma unroll
            for (int ct = 0; ct < 8; ct++) {
                float o = fmaxf(acc[t][ct][reg] + bv[ct], 0.f);
                size_t off = (size_t)r * 128 + ct * 16 + m;
                if (H16) H16[off] = f2bf(o * di);
                if (Hf) Hf[off] = o;
            }
        }
    }
}

// ---------------- pooling phase A: run-length segment accumulation ----------------
__global__ __launch_bounds__(256) void pool_accum(const float* __restrict__ h,
                                                  const int* __restrict__ batch, int N,
                                                  float* __restrict__ psum) {
    int tid = threadIdx.x;
    int f4 = tid & 31;
    int nl = tid >> 5;
    int n0 = blockIdx.x * 256 + nl;
    const float4* h4 = (const float4*)h;
    float4 acc = make_float4(0.f, 0.f, 0.f, 0.f);
    int cur = -1;
    #pragma unroll 4
    for (int i = 0; i < 32; i++) {
        int n = n0 + i * 8;
        if (n >= N) break;
        int g = batch[n];
        if (g != cur) {
            if (cur >= 0) {
                float* d = &psum[(size_t)cur * 128 + f4 * 4];
                atomicAdd(d + 0, acc.x);
                atomicAdd(d + 1, acc.y);
                atomicAdd(d + 2, acc.z);
                atomicAdd(d + 3, acc.w);
            }
            cur = g;
            acc = make_float4(0.f, 0.f, 0.f, 0.f);
        }
        float4 v = h4[(size_t)n * 32 + f4];
        acc.x += v.x; acc.y += v.y; acc.z += v.z; acc.w += v.w;
    }
    if (cur >= 0) {
        float* d = &psum[(size_t)cur * 128 + f4 * 4];
        atomicAdd(d + 0, acc.x);
        atomicAdd(d + 1, acc.y);
        atomicAdd(d + 2, acc.z);
        atomicAdd(d + 3, acc.w);
    }
}

// ---------------- MLP head (divides psum by per-graph count) ----------------
__device__ inline int lower_bound(const int* __restrict__ a, int n, int v) {
    int lo = 0, hi = n;
    while (lo < hi) {
        int m = (lo + hi) >> 1;
        if (a[m] < v) lo = m + 1; else hi = m;
    }
    return lo;
}

__global__ void mlp_kernel(const float* __restrict__ psum,
                           const int* __restrict__ batchL, int NL,
                           const int* __restrict__ batchS, int NS,
                           const float* __restrict__ W1, const float* __restrict__ b1,
                           const float* __restrict__ W2, const float* __restrict__ b2,
                           const float* __restrict__ gamma, const float* __restrict__ beta,
                           const float* __restrict__ outW, const float* __restrict__ outb,
                           float* __restrict__ d_out) {
    __shared__ float row[128];
    __shared__ float row2[128];
    int g = blockIdx.x, t = threadIdx.x;  // 128 threads
    int cnt = (lower_bound(batchL, NL, g + 1) - lower_bound(batchL, NL, g)) +
              (lower_bound(batchS, NS, g + 1) - lower_bound(batchS, NS, g));
    float rcp = 1.f / (float)(cnt > 0 ? cnt : 1);
    row[t] = psum[(size_t)g * 128 + t] * rcp;
    __syncthreads();
    float a = b1[t];
    #pragma unroll 4
    for (int k = 0; k < 128; k++) a += row[k] * W1[k * 128 + t];
    row2[t] = a;  // no relu between lin1 and lin2 in reference
    __syncthreads();
    if (t < 64) {
        float a2 = b2[t];
        #pragma unroll 4
        for (int k = 0; k < 128; k++) a2 += row2[k] * W2[k * 64 + t];
        float rs = rsqrtf(1.0f + 1e-5f);
        float hb = a2 * rs * gamma[t] + beta[t];
        float hr = fmaxf(hb, 0.f);
        d_out[512 + g * 64 + t] = hr;
        float p = hr * outW[t];
        #pragma unroll
        for (int off = 32; off > 0; off >>= 1) p += __shfl_down(p, off, 64);
        if (t == 0) d_out[g] = p + outb[0];
    }
}

// ---------------------------------------------------------------------------
extern "C" void kernel_launch(void* const* d_in, const int* in_sizes, int n_in,
                              void* d_out, int out_size, void* d_ws, size_t ws_size,
                              hipStream_t stream) {
    const float* x_l = (const float*)d_in[0];
    const int*   ei_l = (const int*)d_in[1];
    const float* w_l = (const float*)d_in[2];
    const float* x_s = (const float*)d_in[3];
    const int*   ei_s = (const int*)d_in[4];
    const float* w_s = (const float*)d_in[5];
    const int*   batch_l = (const int*)d_in[6];
    const int*   batch_s = (const int*)d_in[7];

    const int NL = in_sizes[6];           // 100000
    const int NS = in_sizes[7];           // 50000
    const int EL = in_sizes[2];           // 1600000
    const int ES = in_sizes[5];           // 800000

    const float* Wa[4] = {(const float*)d_in[8],  (const float*)d_in[12],
                          (const float*)d_in[16], (const float*)d_in[20]};
    const float* ba[4] = {(const float*)d_in[9],  (const float*)d_in[13],
                          (const float*)d_in[17], (const float*)d_in[21]};
    const float* Wb[4] = {(const float*)d_in[10], (const float*)d_in[14],
                          (const float*)d_in[18], (const float*)d_in[22]};
    const float* bb[4] = {(const float*)d_in[11], (const float*)d_in[15],
                          (const float*)d_in[19], (const float*)d_in[23]};
    const float* lin1_W = (const float*)d_in[24];
    const float* lin1_b = (const float*)d_in[25];
    const float* lin2_W = (const float*)d_in[26];
    const float* lin2_b = (const float*)d_in[27];
    const float* bn_g = (const float*)d_in[28];
    const float* bn_b = (const float*)d_in[29];
    const float* out_W = (const float*)d_in[30];
    const float* out_b = (const float*)d_in[31];
    float* out = (float*)d_out;

    const int* src_l = ei_l;
    const int* dst_l = ei_l + EL;
    const int* src_s = ei_s;
    const int* dst_s = ei_s + ES;

    const int NBL = (NL + 255) >> 8;  // 391
    const int NBS = (NS + 255) >> 8;  // 196

    // ---- workspace carve ----
    char* p = (char*)d_ws;
    auto alloc = [&](size_t bytes) { char* r = p; p += align256(bytes); return r; };
    float* A_l = (float*)alloc((size_t)NL * 128 * 4);   // final-layer fp32 acts
    float* A_s = (float*)alloc((size_t)NS * 128 * 4);
    unsigned short* Z16_l = (unsigned short*)alloc((size_t)NL * 128 * 2);
    unsigned short* Z16_s = (unsigned short*)alloc((size_t)NS * 128 * 2);
    unsigned short* H16_l = (unsigned short*)alloc((size_t)NL * 128 * 2);
    unsigned short* H16_s = (unsigned short*)alloc((size_t)NS * 128 * 2);
    int2*  csr_l  = (int2*)alloc((size_t)EL * 8);
    int2*  csr_s  = (int2*)alloc((size_t)ES * 8);
    int2*  part_l = (int2*)alloc((size_t)EL * 8);
    int2*  part_s = (int2*)alloc((size_t)ES * 8);
    int*   rp_l  = (int*)alloc((size_t)(NL + 1) * 4);
    int*   rp_s  = (int*)alloc((size_t)(NS + 1) * 4);
    float* dinv_l = (float*)alloc((size_t)NL * 4);
    float* dinv_s = (float*)alloc((size_t)NS * 4);
    int*   bhist_l = (int*)alloc(512 * 4);
    int*   bhist_s = (int*)alloc(512 * 4);
    int*   bbase_l = (int*)alloc(512 * 4);
    int*   bbase_s = (int*)alloc(512 * 4);
    int*   bcur_l  = (int*)alloc(512 * 4);
    int*   bcur_s  = (int*)alloc(512 * 4);
    float* psum = (float*)alloc((size_t)512 * 128 * 4);
    unsigned short* WTa[4];
    unsigned short* WTb[4];
    WTa[0] = (unsigned short*)alloc((size_t)128 * 64 * 2);
    for (int i = 1; i < 4; i++) WTa[i] = (unsigned short*)alloc((size_t)128 * 128 * 2);
    WTb[0] = (unsigned short*)alloc((size_t)128 * 32 * 2);
    for (int i = 1; i < 4; i++) WTb[i] = (unsigned short*)alloc((size_t)128 * 128 * 2);
    (void)ws_size; (void)n_in; (void)out_size;

    // ---- zero init ----
    hipMemsetAsync(bhist_l, 0, 512 * 4, stream);
    hipMemsetAsync(bhist_s, 0, 512 * 4, stream);
    hipMemsetAsync(psum, 0, (size_t)512 * 128 * 4, stream);

    // ---- weight cast+transpose ----
    {
        WCastArgs wa;
        for (int i = 0; i < 4; i++) {
            wa.w[i] = Wa[i]; wa.o[i] = WTa[i]; wa.K[i] = (i == 0) ? 64 : 128;
            wa.w[4 + i] = Wb[i]; wa.o[4 + i] = WTb[i]; wa.K[4 + i] = (i == 0) ? 32 : 128;
        }
        cast_w16t<<<dim3(64, 8), 256, 0, stream>>>(wa);
    }

    // ---- CSR build: P0 -> P1 -> P2 -> P3 ----
    bucket_hist<<<(EL + CHUNK - 1) / CHUNK, 256, 0, stream>>>(dst_l, EL, NBL, bhist_l);
    bucket_hist<<<(ES + CHUNK - 1) / CHUNK, 256, 0, stream>>>(dst_s, ES, NBS, bhist_s);
    scan_buckets<<<1, 256, 0, stream>>>(bhist_l, NBL, bbase_l, bcur_l, rp_l, NL, EL);
    scan_buckets<<<1, 256, 0, stream>>>(bhist_s, NBS, bbase_s, bcur_s, rp_s, NS, ES);
    partition_edges<<<(EL + CHUNK - 1) / CHUNK, 256, 0, stream>>>(src_l, dst_l, w_l, EL,
                                                                  NBL, bcur_l, part_l);
    partition_edges<<<(ES + CHUNK - 1) / CHUNK, 256, 0, stream>>>(src_s, dst_s, w_s, ES,
                                                                  NBS, bcur_s, part_s);
    bucket_csr<<<NBL, 256, 0, stream>>>(part_l, bbase_l, NL, rp_l, dinv_l, csr_l);
    bucket_csr<<<NBS, 256, 0, stream>>>(part_s, bbase_s, NS, rp_s, dinv_s, csr_s);

    // ---- layer-0 casts: h~ = bf16(dinv * x) ----
    {
        size_t n8l = (size_t)NL * 64 / 8;
        size_t n8s = (size_t)NS * 32 / 8;
        cast_bf16_scaled<8><<<(int)((n8l + 255) / 256), 256, 0, stream>>>(x_l, n8l, dinv_l,
                                                                          H16_l);
        cast_bf16_scaled<4><<<(int)((n8s + 255) / 256), 256, 0, stream>>>(x_s, n8s, dinv_s,
                                                                          H16_s);
    }

    const int gmL = (NL + 127) / 128;
    const int gmS = (NS + 127) / 128;

    // ---- large branch: layer 0 (K=64), layers 1-3 (K=128) ----
    aggregate_bf16<8><<<(NL + 31) / 32, 256, 0, stream>>>(
        H16_l, NL, rp_l, csr_l, dinv_l, Z16_l);
    gemm_mfma<64><<<gmL, 256, 0, stream>>>(Z16_l, WTa[0], ba[0], dinv_l,
                                           (float*)nullptr, H16_l, NL);
    for (int layer = 1; layer < 4; layer++) {
        aggregate_bf16<16><<<(NL + 15) / 16, 256, 0, stream>>>(
            H16_l, NL, rp_l, csr_l, dinv_l, Z16_l);
        if (layer < 3)
            gemm_mfma<128><<<gmL, 256, 0, stream>>>(Z16_l, WTa[layer], ba[layer], dinv_l,
                                                    (float*)nullptr, H16_l, NL);
        else
            gemm_mfma<128><<<gmL, 256, 0, stream>>>(Z16_l, WTa[layer], ba[layer], dinv_l,
                                                    A_l, (unsigned short*)nullptr, NL);
    }

    // ---- small branch: layer 0 (K=32), layers 1-3 (K=128) ----
    aggregate_bf16<4><<<(NS + 63) / 64, 256, 0, stream>>>(
        H16_s, NS, rp_s, csr_s, dinv_s, Z16_s);
    gemm_mfma<32><<<gmS, 256, 0, stream>>>(Z16_s, WTb[0], bb[0], dinv_s,
                                           (float*)nullptr, H16_s, NS);
    for (int layer = 1; layer < 4; layer++) {
        aggregate_bf16<16><<<(NS + 15) / 16, 256, 0, stream>>>(
            H16_s, NS, rp_s, csr_s, dinv_s, Z16_s);
        if (layer < 3)
            gemm_mfma<128><<<gmS, 256, 0, stream>>>(Z16_s, WTb[layer], bb[layer], dinv_s,
                                                    (float*)nullptr, H16_s, NS);
        else
            gemm_mfma<128><<<gmS, 256, 0, stream>>>(Z16_s, WTb[layer], bb[layer], dinv_s,
                                                    A_s, (unsigned short*)nullptr, NS);
    }

    // ---- pooling + head ----
    pool_accum<<<(NL + 255) / 256, 256, 0, stream>>>(A_l, batch_l, NL, psum);
    pool_accum<<<(NS + 255) / 256, 256, 0, stream>>>(A_s, batch_s, NS, psum);
    mlp_kernel<<<512, 128, 0, stream>>>(psum, batch_l, NL, batch_s, NS,
                                        lin1_W, lin1_b, lin2_W, lin2_b,
                                        bn_g, bn_b, out_W, out_b, out);
}